// Round 14
// baseline (377.336 us; speedup 1.0000x reference)
//
#include <hip/hip_runtime.h>
#include <hip/hip_bf16.h>

#define NEG_SLOPE 0.2f
#define EPSF 1e-16f

typedef __attribute__((ext_vector_type(8))) short bf16x8;
typedef __attribute__((ext_vector_type(4))) float f32x4;

__device__ inline unsigned short f2bf(float x) {
  unsigned int u = __float_as_uint(x);
  return (unsigned short)((u + 0x7fffu + ((u >> 16) & 1u)) >> 16);
}
__device__ inline float bf2f(unsigned short h) {
  return __uint_as_float(((unsigned int)h) << 16);
}

__device__ __forceinline__ void gload16(const void* src, void* dst) {
  __builtin_amdgcn_global_load_lds(
      (const __attribute__((address_space(1))) unsigned int*)src,
      (__attribute__((address_space(3))) unsigned int*)dst, 16, 0, 0);
}

// -------------------- merged: prep_w (blocks 0..127) | count real edges --------------------
// deg pre-zeroed by hipMemsetAsync; self-loops folded into scan3 (+idx), NOT counted here.
// prep_w writes wb, count writes deg — disjoint arrays, safe in one dispatch.
__global__ __launch_bounds__(256) void prep_count_kernel(const float* __restrict__ W,
                                                         unsigned short* __restrict__ wb,
                                                         int* __restrict__ deg,
                                                         const int* __restrict__ ei, int E) {
  const int b = blockIdx.x, tid = threadIdx.x;
  if (b < 128) {
    int idx = b * 256 + tid;  // (k:512, c:64)
    int k = idx >> 6, c = idx & 63;
    float w = W[idx];
    unsigned short h = f2bf(w);
    unsigned short l = f2bf(w - bf2f(h));
    int ch = k >> 5, kin = k & 31;
    int Ap = ((c << 6) + (kin << 1)) ^ ((c & 7) << 4);
    wb[ch * 4096 + (Ap >> 1)] = h;
    wb[ch * 4096 + 2048 + (Ap >> 1)] = l;
  } else {
    int e = (b - 128) * 256 + tid;
    if (e < E) atomicAdd(&deg[ei[E + e]], 1);
  }
}

// exclusive scan, stage 1 (deg in place -> per-block exclusive scan)
__global__ __launch_bounds__(256) void scan1_kernel(int* __restrict__ data, int* __restrict__ blocksum, int N) {
  __shared__ int wave_tot[4];
  int t = threadIdx.x;
  int base = blockIdx.x * 1024;
  int v[4];
  int sum = 0;
#pragma unroll
  for (int i = 0; i < 4; ++i) {
    int idx = base + t * 4 + i;
    v[i] = sum;
    int d = (idx < N) ? data[idx] : 0;
    sum += d;
  }
  int lane = t & 63, wv = t >> 6;
  int x = sum;
#pragma unroll
  for (int ofs = 1; ofs < 64; ofs <<= 1) {
    int y = __shfl_up(x, ofs);
    if (lane >= ofs) x += y;
  }
  if (lane == 63) wave_tot[wv] = x;
  __syncthreads();
  int wofs = 0;
  for (int w = 0; w < wv; ++w) wofs += wave_tot[w];
  int excl_thread = wofs + x - sum;
#pragma unroll
  for (int i = 0; i < 4; ++i) {
    int idx = base + t * 4 + i;
    if (idx < N) data[idx] = excl_thread + v[i];
  }
  if (t == 255) blocksum[blockIdx.x] = wofs + x;
}

__global__ __launch_bounds__(256) void scan2_kernel(int* __restrict__ blocksum, int nb) {
  __shared__ int sm[256];
  int t = threadIdx.x;
  int x = (t < nb) ? blocksum[t] : 0;
  sm[t] = x;
  __syncthreads();
  for (int ofs = 1; ofs < 256; ofs <<= 1) {
    int y = (t >= ofs) ? sm[t - ofs] : 0;
    __syncthreads();
    sm[t] += y;
    __syncthreads();
  }
  if (t < nb) blocksum[t] = sm[t] - x;  // exclusive
}

// rowptr[i] = excl_scan(deg)[i] + i  (+i = one self-loop slot per node)
__global__ __launch_bounds__(256) void scan3_kernel(const int* __restrict__ excl, const int* __restrict__ blocksum,
                                                    int* __restrict__ rowptr, int* __restrict__ cursor,
                                                    int N, int ET) {
  int idx = blockIdx.x * 256 + threadIdx.x;
  if (idx < N) {
    int r = excl[idx] + blocksum[idx >> 10] + idx;
    rowptr[idx] = r;
    cursor[idx] = r;
  }
  if (idx == N) rowptr[N] = ET;
}

// -------------------- MEGA: gemm1 (3-stage async MFMA) + fused att1 + tail scatter ----------
__global__ __launch_bounds__(256) void mega_kernel(const float* __restrict__ x,
                                                   const unsigned short* __restrict__ wb,
                                                   const float* __restrict__ atts,
                                                   const float* __restrict__ attd,
                                                   unsigned short* __restrict__ h1b,
                                                   float* __restrict__ a1s,
                                                   float* __restrict__ a1d, int N,
                                                   const int* __restrict__ ei, int E, int ET,
                                                   int* __restrict__ cursor, int* __restrict__ esrc) {
  __shared__ __align__(16) float As[3][4096];          // 48 KB
  __shared__ __align__(16) unsigned short Bs[3][4096]; // 24 KB
  const int tid = threadIdx.x, wv = tid >> 6, lane = tid & 63;
  const int row0 = blockIdx.x * 128;

  const float* asrc[4];
  int aldo[4];
#pragma unroll
  for (int i = 0; i < 4; ++i) {
    int u = i * 256 + wv * 64 + lane;
    int row = u >> 3, w = u & 7;
    int rg = row0 + row;
    if (rg >= N) rg = N - 1;
    asrc[i] = x + (size_t)rg * 512 + ((w ^ (row & 7)) << 2);
    aldo[i] = (i * 256 + wv * 64) * 4;
  }
  const unsigned short* bsrc[2];
  int bldo[2];
#pragma unroll
  for (int i = 0; i < 2; ++i) {
    int u = i * 256 + wv * 64 + lane;
    bsrc[i] = wb + (size_t)u * 8;
    bldo[i] = (i * 256 + wv * 64) * 8;
  }

  const int kofs = (lane >> 4) * 8;
  const int cbase = lane & 15;
  int ardo[2][2];
#pragma unroll
  for (int rt = 0; rt < 2; ++rt) {
    int r = wv * 32 + rt * 16 + cbase;
#pragma unroll
    for (int h = 0; h < 2; ++h)
      ardo[rt][h] = r * 32 + ((((kofs >> 2) + h) ^ (r & 7)) << 2);
  }
  int brdo[4];
#pragma unroll
  for (int ct = 0; ct < 4; ++ct) {
    int c = ct * 16 + cbase;
    brdo[ct] = (((c << 6) + (kofs << 1)) ^ ((c & 7) << 4)) >> 1;
  }

  f32x4 acc[2][4] = {};

  auto stage = [&](int b, int ch) {
#pragma unroll
    for (int i = 0; i < 4; ++i) gload16(asrc[i] + ch * 32, &As[b][aldo[i]]);
#pragma unroll
    for (int i = 0; i < 2; ++i) gload16(bsrc[i] + ch * 4096, &Bs[b][bldo[i]]);
  };

  stage(0, 0);
  stage(1, 1);
  for (int i = 0; i < 16; ++i) {
    const int b = i % 3;
    if (i < 14) {
      stage((i + 2) % 3, i + 2);
      asm volatile("s_waitcnt vmcnt(12)" ::: "memory");
    } else if (i == 14) {
      asm volatile("s_waitcnt vmcnt(6)" ::: "memory");
    } else {
      asm volatile("s_waitcnt vmcnt(0)" ::: "memory");
    }
    __builtin_amdgcn_s_barrier();
    __builtin_amdgcn_sched_barrier(0);

#pragma unroll
    for (int rt = 0; rt < 2; ++rt) {
      float4 a0 = *(const float4*)(&As[b][ardo[rt][0]]);
      float4 a1 = *(const float4*)(&As[b][ardo[rt][1]]);
      float av[8] = {a0.x, a0.y, a0.z, a0.w, a1.x, a1.y, a1.z, a1.w};
      bf16x8 ah, al;
#pragma unroll
      for (int j = 0; j < 8; ++j) {
        unsigned int u = __float_as_uint(av[j]);
        ah[j] = (short)(unsigned short)(u >> 16);
        float lo = av[j] - __uint_as_float(u & 0xffff0000u);
        al[j] = (short)(unsigned short)(__float_as_uint(lo) >> 16);
      }
#pragma unroll
      for (int ct = 0; ct < 4; ++ct) {
        bf16x8 bh = *(const bf16x8*)(&Bs[b][brdo[ct]]);
        bf16x8 bl = *(const bf16x8*)(&Bs[b][brdo[ct] + 2048]);
        acc[rt][ct] = __builtin_amdgcn_mfma_f32_16x16x32_bf16(ah, bh, acc[rt][ct], 0, 0, 0);
        acc[rt][ct] = __builtin_amdgcn_mfma_f32_16x16x32_bf16(al, bh, acc[rt][ct], 0, 0, 0);
        acc[rt][ct] = __builtin_amdgcn_mfma_f32_16x16x32_bf16(ah, bl, acc[rt][ct], 0, 0, 0);
      }
    }
    asm volatile("s_waitcnt lgkmcnt(0)" ::: "memory");
    __builtin_amdgcn_s_barrier();
  }

  // gemm epilogue: h1 bf16 store + fused attention scalars
  {
    float wS[4], wD[4];
#pragma unroll
    for (int ct = 0; ct < 4; ++ct) {
      wS[ct] = atts[ct * 16 + cbase];
      wD[ct] = attd[ct * 16 + cbase];
    }
#pragma unroll
    for (int rt = 0; rt < 2; ++rt) {
#pragma unroll
      for (int ct = 0; ct < 4; ++ct) {
#pragma unroll
        for (int j = 0; j < 4; ++j) {
          int r = row0 + wv * 32 + rt * 16 + (lane >> 4) * 4 + j;
          float a = acc[rt][ct][j];
          if (r < N) h1b[(size_t)r * 64 + ct * 16 + cbase] = f2bf(a);
          float ps = a * wS[ct], pd = a * wD[ct];
          ps += __shfl_xor(ps, 1); pd += __shfl_xor(pd, 1);
          ps += __shfl_xor(ps, 2); pd += __shfl_xor(pd, 2);
          ps += __shfl_xor(ps, 4); pd += __shfl_xor(pd, 4);
          if ((lane & 7) == 0 && r < N) {
            int h = ct * 2 + ((lane >> 3) & 1);
            a1s[r * 8 + h] = ps;
            a1d[r * 8 + h] = pd;
          }
        }
      }
    }
  }

  // ---- tail: XCD-class-filtered scatter slice (cursor initialized by scan3) ----
  {
    const int cls = blockIdx.x & 7;
    const int nlo = (int)(((long long)N * cls) >> 3);
    const int nhi = (int)(((long long)N * (cls + 1)) >> 3);
    const int chunk = blockIdx.x >> 3;
    const int nch = ((int)gridDim.x - cls + 7) >> 3;  // blocks in this class
    const long long stride = (long long)nch * 256;
    for (long long e = (long long)chunk * 256 + tid; e < ET; e += stride) {
      int s, d;
      if (e < E) { d = ei[E + e]; s = ei[e]; }
      else       { d = (int)(e - E); s = d; }
      if (d >= nlo && d < nhi) {
        int pos = atomicAdd(&cursor[d], 1);
        esrc[pos] = s;
      }
    }
  }
}

// -------------------- agg1: TWO nodes per wave (32 lanes each), lane = 2 channels ----------
__global__ __launch_bounds__(256) void agg1_kernel(const int* __restrict__ rowptr, const int* __restrict__ esrc,
                                                   const float* __restrict__ a1s, const float* __restrict__ a1d,
                                                   const unsigned short* __restrict__ h1b,
                                                   const float* __restrict__ bias1,
                                                   unsigned short* __restrict__ h2b, int N) {
  const int wid = (blockIdx.x * 256 + threadIdx.x) >> 6;
  const int lane = threadIdx.x & 63;
  const int half = lane >> 5, l = lane & 31;
  const int nA = wid * 2;
  if (nA >= N) return;
  const int n = nA + half;
  const bool nvalid = n < N;
  const int nc = nvalid ? n : nA;
  const int h = l >> 2;
  const int c2 = l * 2;

  const float ad = a1d[(unsigned)nc * 8 + h];
  const int beg = rowptr[nc];
  const int deg = nvalid ? (rowptr[nc + 1] - beg) : 0;
  const int degO = __shfl_xor(deg, 32);
  const int dmax = max(deg, degO);
  const int dcl = max(deg, 1) - 1;

  float acc0 = 0.f, acc1 = 0.f, wsum = 0.f;
  for (int it = 0; it < dmax; it += 2) {
    int k0 = beg + min(it, dcl);
    int k1 = beg + min(it + 1, dcl);
    float m0 = (it < deg) ? 1.f : 0.f;
    float m1 = (it + 1 < deg) ? 1.f : 0.f;
    int s0 = esrc[k0], s1 = esrc[k1];
    unsigned int g0 = *(const unsigned int*)(h1b + ((unsigned)s0 * 64 + c2));
    unsigned int g1 = *(const unsigned int*)(h1b + ((unsigned)s1 * 64 + c2));
    float al0 = a1s[(unsigned)s0 * 8 + h] + ad;
    float al1 = a1s[(unsigned)s1 * 8 + h] + ad;
    al0 = fmaxf(al0, NEG_SLOPE * al0);
    al1 = fmaxf(al1, NEG_SLOPE * al1);
    float w0 = __expf(al0) * m0;
    float w1 = __expf(al1) * m1;
    acc0 = fmaf(w0, bf2f((unsigned short)(g0 & 0xffff)), acc0);
    acc1 = fmaf(w0, bf2f((unsigned short)(g0 >> 16)), acc1);
    acc0 = fmaf(w1, bf2f((unsigned short)(g1 & 0xffff)), acc0);
    acc1 = fmaf(w1, bf2f((unsigned short)(g1 >> 16)), acc1);
    wsum += w0 + w1;
  }
  float inv = 1.f / (wsum + EPSF);
  float2 b2 = *(const float2*)(bias1 + c2);
  float v0 = acc0 * inv + b2.x;
  float v1 = acc1 * inv + b2.y;
  v0 = (v0 > 0.f) ? v0 : expm1f(v0);
  v1 = (v1 > 0.f) ? v1 : expm1f(v1);
  if (nvalid) {
    unsigned int pack = (unsigned int)f2bf(v0) | ((unsigned int)f2bf(v1) << 16);
    *(unsigned int*)(h2b + ((unsigned)n * 64 + c2)) = pack;
  }
}

// -------------------- layer2 projection g = h2 @ W2 + attention scalars --------------------
__global__ __launch_bounds__(256) void l2_proj_kernel(const unsigned short* __restrict__ h2b,
                                                      const float* __restrict__ W2,
                                                      const float* __restrict__ atts, const float* __restrict__ attd,
                                                      unsigned short* __restrict__ gb, float* __restrict__ a2s,
                                                      float* __restrict__ a2d, int N) {
  __shared__ float w[1024];
  int tid = threadIdx.x;
  for (int i = tid; i < 1024; i += 256) w[i] = W2[i];
  __syncthreads();
  int gid = blockIdx.x * 256 + tid;
  int n = gid >> 4, c = gid & 15;
  if (n >= N) return;
  const unsigned short* hr = h2b + (size_t)n * 64;
  float acc = 0.f;
#pragma unroll
  for (int k8 = 0; k8 < 8; ++k8) {
    bf16x8 hv = *(const bf16x8*)(hr + k8 * 8);
#pragma unroll
    for (int j = 0; j < 8; ++j)
      acc = fmaf(bf2f((unsigned short)hv[j]), w[(k8 * 8 + j) * 16 + c], acc);
  }
  gb[(size_t)n * 16 + c] = f2bf(acc);
  float ps = acc * atts[c], pd = acc * attd[c];
#pragma unroll
  for (int m = 1; m < 16; m <<= 1) { ps += __shfl_xor(ps, m); pd += __shfl_xor(pd, m); }
  if (c == 0) { a2s[n] = ps; a2d[n] = pd; }
}

// -------------------- agg2: TWO nodes per wave + bias + softmax (fused final) ----------
__global__ __launch_bounds__(256) void agg2_kernel(const int* __restrict__ rowptr, const int* __restrict__ esrc,
                                                   const float* __restrict__ a2s, const float* __restrict__ a2d,
                                                   const unsigned short* __restrict__ gb,
                                                   const float* __restrict__ bias2,
                                                   float* __restrict__ out_sm, float* __restrict__ emb, int N) {
  const int wid = (blockIdx.x * 256 + threadIdx.x) >> 6;
  const int lane = threadIdx.x & 63;
  const int half = lane >> 5, l = lane & 31;
  const int nA = wid * 2;
  if (nA >= N) return;
  const int n = nA + half;
  const bool nvalid = n < N;
  const int nc = nvalid ? n : nA;
  const int c = l & 15, sub = l >> 4;

  const float ad = a2d[nc];
  const int beg = rowptr[nc];
  const int deg = nvalid ? (rowptr[nc + 1] - beg) : 0;
  const int degO = __shfl_xor(deg, 32);
  const int dmax = max(deg, degO);
  const int dcl = max(deg, 1) - 1;

  float acc = 0.f, wsum = 0.f;
  for (int it = 0; it < dmax; it += 2) {
    int k = beg + min(it + sub, dcl);
    float m = (it + sub < deg) ? 1.f : 0.f;
    int s = esrc[k];
    float al = a2s[s] + ad;
    al = fmaxf(al, NEG_SLOPE * al);
    float w = __expf(al) * m;
    acc = fmaf(w, bf2f(gb[(unsigned)s * 16 + c]), acc);
    wsum += w;
  }
  acc += __shfl_xor(acc, 16);
  wsum += __shfl_xor(wsum, 16);
  float v = acc / (wsum + EPSF) + bias2[c];
  float mx = v;
#pragma unroll
  for (int k2 = 1; k2 < 16; k2 <<= 1) mx = fmaxf(mx, __shfl_xor(mx, k2));
  float e = __expf(v - mx);
  float ssum = e;
#pragma unroll
  for (int k2 = 1; k2 < 16; k2 <<= 1) ssum += __shfl_xor(ssum, k2);
  if (sub == 0 && nvalid) {
    emb[(size_t)n * 16 + c] = v;
    out_sm[(size_t)n * 16 + c] = e / ssum;
  }
}

extern "C" void kernel_launch(void* const* d_in, const int* in_sizes, int n_in,
                              void* d_out, int out_size, void* d_ws, size_t ws_size,
                              hipStream_t stream) {
  const float* x     = (const float*)d_in[0];
  const int*   ei    = (const int*)d_in[1];
  const float* W1    = (const float*)d_in[2];
  const float* atts1 = (const float*)d_in[3];
  const float* attd1 = (const float*)d_in[4];
  const float* bias1 = (const float*)d_in[5];
  const float* W2    = (const float*)d_in[6];
  const float* atts2 = (const float*)d_in[7];
  const float* attd2 = (const float*)d_in[8];
  const float* bias2 = (const float*)d_in[9];

  const int N = in_sizes[0] / 512;
  const int E = in_sizes[1] / 2;
  const int ET = E + N;

  char* wp = (char*)d_ws;
  unsigned short* h1b = (unsigned short*)wp;        wp += (size_t)N * 64 * 2;
  unsigned short* h2b = (unsigned short*)wp;        wp += (size_t)N * 64 * 2;
  float* a1s = (float*)wp;                          wp += (size_t)N * 8 * 4;
  float* a1d = (float*)wp;                          wp += (size_t)N * 8 * 4;
  unsigned short* gb = (unsigned short*)wp;         wp += (size_t)N * 16 * 2;
  float* a2s = (float*)wp;                          wp += (size_t)N * 4;
  float* a2d = (float*)wp;                          wp += (size_t)N * 4;
  int* deg = (int*)wp;                              wp += (size_t)N * 4;
  int* rowptr = (int*)wp;                           wp += (size_t)(N + 1) * 4;
  int* cursor = (int*)wp;                           wp += (size_t)N * 4;
  int* blocksum = (int*)wp;                         wp += 256 * 4;
  int* esrc = (int*)wp;                             wp += (size_t)ET * 4;
  unsigned short* wb = (unsigned short*)wp;         wp += 512 * 64 * 2 * 2;

  float* out_sm = (float*)d_out;            // softmax output [N,16]
  float* emb    = out_sm + (size_t)N * 16;  // node_embeddings [N,16]

  const int nb = (N + 1023) / 1024;
  const int nCnt = (E + 255) / 256;

  // phase 0: zero deg, then prep_w | count (disjoint outputs, one dispatch — race-free)
  hipMemsetAsync(deg, 0, (size_t)N * sizeof(int), stream);
  prep_count_kernel<<<128 + nCnt, 256, 0, stream>>>(W1, wb, deg, ei, E);
  // CSR scans; scan3 adds +idx (self-loop slot per node)
  scan1_kernel<<<nb, 256, 0, stream>>>(deg, blocksum, N);
  scan2_kernel<<<1, 256, 0, stream>>>(blocksum, nb);
  scan3_kernel<<<(N + 256) / 256, 256, 0, stream>>>(deg, blocksum, rowptr, cursor, N, ET);

  // MEGA: gemm1 + fused att1 + tail scatter (scatter hides under gemm stalls)
  mega_kernel<<<(N + 127) / 128, 256, 0, stream>>>(x, wb, atts1, attd1, h1b, a1s, a1d, N,
                                                   ei, E, ET, cursor, esrc);

  // layer 1 aggregation, layer 2
  agg1_kernel<<<(N + 7) / 8, 256, 0, stream>>>(rowptr, esrc, a1s, a1d, h1b, bias1, h2b, N);
  l2_proj_kernel<<<(N * 16 + 255) / 256, 256, 0, stream>>>(h2b, W2, atts2, attd2, gb, a2s, a2d, N);
  agg2_kernel<<<(N + 7) / 8, 256, 0, stream>>>(rowptr, esrc, a2s, a2d, gb, bias2, out_sm, emb, N);
}

// Round 15
// 341.227 us; speedup vs baseline: 1.1058x; 1.1058x over previous
//
#include <hip/hip_runtime.h>
#include <hip/hip_bf16.h>

#define NEG_SLOPE 0.2f
#define EPSF 1e-16f

typedef __attribute__((ext_vector_type(8))) short bf16x8;
typedef __attribute__((ext_vector_type(4))) float f32x4;

__device__ inline unsigned short f2bf(float x) {
  unsigned int u = __float_as_uint(x);
  return (unsigned short)((u + 0x7fffu + ((u >> 16) & 1u)) >> 16);
}
__device__ inline float bf2f(unsigned short h) {
  return __uint_as_float(((unsigned int)h) << 16);
}

__device__ __forceinline__ void gload16(const void* src, void* dst) {
  __builtin_amdgcn_global_load_lds(
      (const __attribute__((address_space(1))) unsigned int*)src,
      (__attribute__((address_space(3))) unsigned int*)dst, 16, 0, 0);
}

// -------------------- merged: prep_w (blocks 0..127) | count real edges --------------------
// deg pre-zeroed by hipMemsetAsync; self-loops folded into scan3 (+idx), NOT counted here.
__global__ __launch_bounds__(256) void prep_count_kernel(const float* __restrict__ W,
                                                         unsigned short* __restrict__ wb,
                                                         int* __restrict__ deg,
                                                         const int* __restrict__ ei, int E) {
  const int b = blockIdx.x, tid = threadIdx.x;
  if (b < 128) {
    int idx = b * 256 + tid;  // (k:512, c:64)
    int k = idx >> 6, c = idx & 63;
    float w = W[idx];
    unsigned short h = f2bf(w);
    unsigned short l = f2bf(w - bf2f(h));
    int ch = k >> 5, kin = k & 31;
    int Ap = ((c << 6) + (kin << 1)) ^ ((c & 7) << 4);
    wb[ch * 4096 + (Ap >> 1)] = h;
    wb[ch * 4096 + 2048 + (Ap >> 1)] = l;
  } else {
    int e = (b - 128) * 256 + tid;
    if (e < E) atomicAdd(&deg[ei[E + e]], 1);
  }
}

// exclusive scan, stage 1
__global__ __launch_bounds__(256) void scan1_kernel(int* __restrict__ data, int* __restrict__ blocksum, int N) {
  __shared__ int wave_tot[4];
  int t = threadIdx.x;
  int base = blockIdx.x * 1024;
  int v[4];
  int sum = 0;
#pragma unroll
  for (int i = 0; i < 4; ++i) {
    int idx = base + t * 4 + i;
    v[i] = sum;
    int d = (idx < N) ? data[idx] : 0;
    sum += d;
  }
  int lane = t & 63, wv = t >> 6;
  int x = sum;
#pragma unroll
  for (int ofs = 1; ofs < 64; ofs <<= 1) {
    int y = __shfl_up(x, ofs);
    if (lane >= ofs) x += y;
  }
  if (lane == 63) wave_tot[wv] = x;
  __syncthreads();
  int wofs = 0;
  for (int w = 0; w < wv; ++w) wofs += wave_tot[w];
  int excl_thread = wofs + x - sum;
#pragma unroll
  for (int i = 0; i < 4; ++i) {
    int idx = base + t * 4 + i;
    if (idx < N) data[idx] = excl_thread + v[i];
  }
  if (t == 255) blocksum[blockIdx.x] = wofs + x;
}

__global__ __launch_bounds__(256) void scan2_kernel(int* __restrict__ blocksum, int nb) {
  __shared__ int sm[256];
  int t = threadIdx.x;
  int x = (t < nb) ? blocksum[t] : 0;
  sm[t] = x;
  __syncthreads();
  for (int ofs = 1; ofs < 256; ofs <<= 1) {
    int y = (t >= ofs) ? sm[t - ofs] : 0;
    __syncthreads();
    sm[t] += y;
    __syncthreads();
  }
  if (t < nb) blocksum[t] = sm[t] - x;  // exclusive
}

// rowptr[i] = excl_scan(deg)[i] + i  (+i = one self-loop slot per node)
__global__ __launch_bounds__(256) void scan3_kernel(const int* __restrict__ excl, const int* __restrict__ blocksum,
                                                    int* __restrict__ rowptr, int* __restrict__ cursor,
                                                    int N, int ET) {
  int idx = blockIdx.x * 256 + threadIdx.x;
  if (idx < N) {
    int r = excl[idx] + blocksum[idx >> 10] + idx;
    rowptr[idx] = r;
    cursor[idx] = r;
  }
  if (idx == N) rowptr[N] = ET;
}

// XCD-class-filtered scatter (keeps cursor/esrc writes XCD-local); 8192 dedicated blocks
__global__ __launch_bounds__(256) void scatter_kernel(const int* __restrict__ ei, int E, int ET,
                                                      int* __restrict__ cursor, int* __restrict__ esrc, int N) {
  const int cls = blockIdx.x & 7;
  const int nlo = (int)(((long long)N * cls) >> 3);
  const int nhi = (int)(((long long)N * (cls + 1)) >> 3);
  const int chunk = blockIdx.x >> 3;
  const int nchunks = gridDim.x >> 3;
  const long long stride = (long long)nchunks * 256;
  for (long long e = (long long)chunk * 256 + threadIdx.x; e < ET; e += stride) {
    int s, d;
    if (e < E) { d = ei[E + e]; s = ei[e]; }
    else       { d = (int)(e - E); s = d; }
    if (d >= nlo && d < nhi) {
      int pos = atomicAdd(&cursor[d], 1);
      esrc[pos] = s;
    }
  }
}

// -------------------- GEMM1 + fused att1: 3-stage async MFMA pipeline --------------------
__global__ __launch_bounds__(256) void gemm1_kernel(const float* __restrict__ x,
                                                    const unsigned short* __restrict__ wb,
                                                    const float* __restrict__ atts,
                                                    const float* __restrict__ attd,
                                                    unsigned short* __restrict__ h1b,
                                                    float* __restrict__ a1s,
                                                    float* __restrict__ a1d, int N) {
  __shared__ __align__(16) float As[3][4096];          // 48 KB
  __shared__ __align__(16) unsigned short Bs[3][4096]; // 24 KB
  const int tid = threadIdx.x, wv = tid >> 6, lane = tid & 63;
  const int row0 = blockIdx.x * 128;

  const float* asrc[4];
  int aldo[4];
#pragma unroll
  for (int i = 0; i < 4; ++i) {
    int u = i * 256 + wv * 64 + lane;
    int row = u >> 3, w = u & 7;
    int rg = row0 + row;
    if (rg >= N) rg = N - 1;
    asrc[i] = x + (size_t)rg * 512 + ((w ^ (row & 7)) << 2);
    aldo[i] = (i * 256 + wv * 64) * 4;
  }
  const unsigned short* bsrc[2];
  int bldo[2];
#pragma unroll
  for (int i = 0; i < 2; ++i) {
    int u = i * 256 + wv * 64 + lane;
    bsrc[i] = wb + (size_t)u * 8;
    bldo[i] = (i * 256 + wv * 64) * 8;
  }

  const int kofs = (lane >> 4) * 8;
  const int cbase = lane & 15;
  int ardo[2][2];
#pragma unroll
  for (int rt = 0; rt < 2; ++rt) {
    int r = wv * 32 + rt * 16 + cbase;
#pragma unroll
    for (int h = 0; h < 2; ++h)
      ardo[rt][h] = r * 32 + ((((kofs >> 2) + h) ^ (r & 7)) << 2);
  }
  int brdo[4];
#pragma unroll
  for (int ct = 0; ct < 4; ++ct) {
    int c = ct * 16 + cbase;
    brdo[ct] = (((c << 6) + (kofs << 1)) ^ ((c & 7) << 4)) >> 1;
  }

  f32x4 acc[2][4] = {};

  auto stage = [&](int b, int ch) {
#pragma unroll
    for (int i = 0; i < 4; ++i) gload16(asrc[i] + ch * 32, &As[b][aldo[i]]);
#pragma unroll
    for (int i = 0; i < 2; ++i) gload16(bsrc[i] + ch * 4096, &Bs[b][bldo[i]]);
  };

  stage(0, 0);
  stage(1, 1);
  for (int i = 0; i < 16; ++i) {
    const int b = i % 3;
    if (i < 14) {
      stage((i + 2) % 3, i + 2);
      asm volatile("s_waitcnt vmcnt(12)" ::: "memory");
    } else if (i == 14) {
      asm volatile("s_waitcnt vmcnt(6)" ::: "memory");
    } else {
      asm volatile("s_waitcnt vmcnt(0)" ::: "memory");
    }
    __builtin_amdgcn_s_barrier();
    __builtin_amdgcn_sched_barrier(0);

#pragma unroll
    for (int rt = 0; rt < 2; ++rt) {
      float4 a0 = *(const float4*)(&As[b][ardo[rt][0]]);
      float4 a1 = *(const float4*)(&As[b][ardo[rt][1]]);
      float av[8] = {a0.x, a0.y, a0.z, a0.w, a1.x, a1.y, a1.z, a1.w};
      bf16x8 ah, al;
#pragma unroll
      for (int j = 0; j < 8; ++j) {
        unsigned int u = __float_as_uint(av[j]);
        ah[j] = (short)(unsigned short)(u >> 16);
        float lo = av[j] - __uint_as_float(u & 0xffff0000u);
        al[j] = (short)(unsigned short)(__float_as_uint(lo) >> 16);
      }
#pragma unroll
      for (int ct = 0; ct < 4; ++ct) {
        bf16x8 bh = *(const bf16x8*)(&Bs[b][brdo[ct]]);
        bf16x8 bl = *(const bf16x8*)(&Bs[b][brdo[ct] + 2048]);
        acc[rt][ct] = __builtin_amdgcn_mfma_f32_16x16x32_bf16(ah, bh, acc[rt][ct], 0, 0, 0);
        acc[rt][ct] = __builtin_amdgcn_mfma_f32_16x16x32_bf16(al, bh, acc[rt][ct], 0, 0, 0);
        acc[rt][ct] = __builtin_amdgcn_mfma_f32_16x16x32_bf16(ah, bl, acc[rt][ct], 0, 0, 0);
      }
    }
    asm volatile("s_waitcnt lgkmcnt(0)" ::: "memory");
    __builtin_amdgcn_s_barrier();
  }

  float wS[4], wD[4];
#pragma unroll
  for (int ct = 0; ct < 4; ++ct) {
    wS[ct] = atts[ct * 16 + cbase];
    wD[ct] = attd[ct * 16 + cbase];
  }
#pragma unroll
  for (int rt = 0; rt < 2; ++rt) {
#pragma unroll
    for (int ct = 0; ct < 4; ++ct) {
#pragma unroll
      for (int j = 0; j < 4; ++j) {
        int r = row0 + wv * 32 + rt * 16 + (lane >> 4) * 4 + j;
        float a = acc[rt][ct][j];
        if (r < N) h1b[(size_t)r * 64 + ct * 16 + cbase] = f2bf(a);
        float ps = a * wS[ct], pd = a * wD[ct];
        ps += __shfl_xor(ps, 1); pd += __shfl_xor(pd, 1);
        ps += __shfl_xor(ps, 2); pd += __shfl_xor(pd, 2);
        ps += __shfl_xor(ps, 4); pd += __shfl_xor(pd, 4);
        if ((lane & 7) == 0 && r < N) {
          int h = ct * 2 + ((lane >> 3) & 1);
          a1s[r * 8 + h] = ps;
          a1d[r * 8 + h] = pd;
        }
      }
    }
  }
}

// -------------------- agg1: TWO nodes per wave (32 lanes each), lane = 2 channels ----------
__global__ __launch_bounds__(256) void agg1_kernel(const int* __restrict__ rowptr, const int* __restrict__ esrc,
                                                   const float* __restrict__ a1s, const float* __restrict__ a1d,
                                                   const unsigned short* __restrict__ h1b,
                                                   const float* __restrict__ bias1,
                                                   unsigned short* __restrict__ h2b, int N) {
  const int wid = (blockIdx.x * 256 + threadIdx.x) >> 6;
  const int lane = threadIdx.x & 63;
  const int half = lane >> 5, l = lane & 31;
  const int nA = wid * 2;
  if (nA >= N) return;
  const int n = nA + half;
  const bool nvalid = n < N;
  const int nc = nvalid ? n : nA;
  const int h = l >> 2;
  const int c2 = l * 2;

  const float ad = a1d[(unsigned)nc * 8 + h];
  const int beg = rowptr[nc];
  const int deg = nvalid ? (rowptr[nc + 1] - beg) : 0;
  const int degO = __shfl_xor(deg, 32);
  const int dmax = max(deg, degO);
  const int dcl = max(deg, 1) - 1;

  float acc0 = 0.f, acc1 = 0.f, wsum = 0.f;
  for (int it = 0; it < dmax; it += 2) {
    int k0 = beg + min(it, dcl);
    int k1 = beg + min(it + 1, dcl);
    float m0 = (it < deg) ? 1.f : 0.f;
    float m1 = (it + 1 < deg) ? 1.f : 0.f;
    int s0 = esrc[k0], s1 = esrc[k1];
    unsigned int g0 = *(const unsigned int*)(h1b + ((unsigned)s0 * 64 + c2));
    unsigned int g1 = *(const unsigned int*)(h1b + ((unsigned)s1 * 64 + c2));
    float al0 = a1s[(unsigned)s0 * 8 + h] + ad;
    float al1 = a1s[(unsigned)s1 * 8 + h] + ad;
    al0 = fmaxf(al0, NEG_SLOPE * al0);
    al1 = fmaxf(al1, NEG_SLOPE * al1);
    float w0 = __expf(al0) * m0;
    float w1 = __expf(al1) * m1;
    acc0 = fmaf(w0, bf2f((unsigned short)(g0 & 0xffff)), acc0);
    acc1 = fmaf(w0, bf2f((unsigned short)(g0 >> 16)), acc1);
    acc0 = fmaf(w1, bf2f((unsigned short)(g1 & 0xffff)), acc0);
    acc1 = fmaf(w1, bf2f((unsigned short)(g1 >> 16)), acc1);
    wsum += w0 + w1;
  }
  float inv = 1.f / (wsum + EPSF);
  float2 b2 = *(const float2*)(bias1 + c2);
  float v0 = acc0 * inv + b2.x;
  float v1 = acc1 * inv + b2.y;
  v0 = (v0 > 0.f) ? v0 : expm1f(v0);
  v1 = (v1 > 0.f) ? v1 : expm1f(v1);
  if (nvalid) {
    unsigned int pack = (unsigned int)f2bf(v0) | ((unsigned int)f2bf(v1) << 16);
    *(unsigned int*)(h2b + ((unsigned)n * 64 + c2)) = pack;
  }
}

// -------------------- layer2 projection g = h2 @ W2 + attention scalars --------------------
__global__ __launch_bounds__(256) void l2_proj_kernel(const unsigned short* __restrict__ h2b,
                                                      const float* __restrict__ W2,
                                                      const float* __restrict__ atts, const float* __restrict__ attd,
                                                      unsigned short* __restrict__ gb, float* __restrict__ a2s,
                                                      float* __restrict__ a2d, int N) {
  __shared__ float w[1024];
  int tid = threadIdx.x;
  for (int i = tid; i < 1024; i += 256) w[i] = W2[i];
  __syncthreads();
  int gid = blockIdx.x * 256 + tid;
  int n = gid >> 4, c = gid & 15;
  if (n >= N) return;
  const unsigned short* hr = h2b + (size_t)n * 64;
  float acc = 0.f;
#pragma unroll
  for (int k8 = 0; k8 < 8; ++k8) {
    bf16x8 hv = *(const bf16x8*)(hr + k8 * 8);
#pragma unroll
    for (int j = 0; j < 8; ++j)
      acc = fmaf(bf2f((unsigned short)hv[j]), w[(k8 * 8 + j) * 16 + c], acc);
  }
  gb[(size_t)n * 16 + c] = f2bf(acc);
  float ps = acc * atts[c], pd = acc * attd[c];
#pragma unroll
  for (int m = 1; m < 16; m <<= 1) { ps += __shfl_xor(ps, m); pd += __shfl_xor(pd, m); }
  if (c == 0) { a2s[n] = ps; a2d[n] = pd; }
}

// -------------------- agg2: TWO nodes per wave + bias + softmax (fused final) ----------
__global__ __launch_bounds__(256) void agg2_kernel(const int* __restrict__ rowptr, const int* __restrict__ esrc,
                                                   const float* __restrict__ a2s, const float* __restrict__ a2d,
                                                   const unsigned short* __restrict__ gb,
                                                   const float* __restrict__ bias2,
                                                   float* __restrict__ out_sm, float* __restrict__ emb, int N) {
  const int wid = (blockIdx.x * 256 + threadIdx.x) >> 6;
  const int lane = threadIdx.x & 63;
  const int half = lane >> 5, l = lane & 31;
  const int nA = wid * 2;
  if (nA >= N) return;
  const int n = nA + half;
  const bool nvalid = n < N;
  const int nc = nvalid ? n : nA;
  const int c = l & 15, sub = l >> 4;

  const float ad = a2d[nc];
  const int beg = rowptr[nc];
  const int deg = nvalid ? (rowptr[nc + 1] - beg) : 0;
  const int degO = __shfl_xor(deg, 32);
  const int dmax = max(deg, degO);
  const int dcl = max(deg, 1) - 1;

  float acc = 0.f, wsum = 0.f;
  for (int it = 0; it < dmax; it += 2) {
    int k = beg + min(it + sub, dcl);
    float m = (it + sub < deg) ? 1.f : 0.f;
    int s = esrc[k];
    float al = a2s[s] + ad;
    al = fmaxf(al, NEG_SLOPE * al);
    float w = __expf(al) * m;
    acc = fmaf(w, bf2f(gb[(unsigned)s * 16 + c]), acc);
    wsum += w;
  }
  acc += __shfl_xor(acc, 16);
  wsum += __shfl_xor(wsum, 16);
  float v = acc / (wsum + EPSF) + bias2[c];
  float mx = v;
#pragma unroll
  for (int k2 = 1; k2 < 16; k2 <<= 1) mx = fmaxf(mx, __shfl_xor(mx, k2));
  float e = __expf(v - mx);
  float ssum = e;
#pragma unroll
  for (int k2 = 1; k2 < 16; k2 <<= 1) ssum += __shfl_xor(ssum, k2);
  if (sub == 0 && nvalid) {
    emb[(size_t)n * 16 + c] = v;
    out_sm[(size_t)n * 16 + c] = e / ssum;
  }
}

extern "C" void kernel_launch(void* const* d_in, const int* in_sizes, int n_in,
                              void* d_out, int out_size, void* d_ws, size_t ws_size,
                              hipStream_t stream) {
  const float* x     = (const float*)d_in[0];
  const int*   ei    = (const int*)d_in[1];
  const float* W1    = (const float*)d_in[2];
  const float* atts1 = (const float*)d_in[3];
  const float* attd1 = (const float*)d_in[4];
  const float* bias1 = (const float*)d_in[5];
  const float* W2    = (const float*)d_in[6];
  const float* atts2 = (const float*)d_in[7];
  const float* attd2 = (const float*)d_in[8];
  const float* bias2 = (const float*)d_in[9];

  const int N = in_sizes[0] / 512;
  const int E = in_sizes[1] / 2;
  const int ET = E + N;

  char* wp = (char*)d_ws;
  unsigned short* h1b = (unsigned short*)wp;        wp += (size_t)N * 64 * 2;
  unsigned short* h2b = (unsigned short*)wp;        wp += (size_t)N * 64 * 2;
  float* a1s = (float*)wp;                          wp += (size_t)N * 8 * 4;
  float* a1d = (float*)wp;                          wp += (size_t)N * 8 * 4;
  unsigned short* gb = (unsigned short*)wp;         wp += (size_t)N * 16 * 2;
  float* a2s = (float*)wp;                          wp += (size_t)N * 4;
  float* a2d = (float*)wp;                          wp += (size_t)N * 4;
  int* deg = (int*)wp;                              wp += (size_t)N * 4;
  int* rowptr = (int*)wp;                           wp += (size_t)(N + 1) * 4;
  int* cursor = (int*)wp;                           wp += (size_t)N * 4;
  int* blocksum = (int*)wp;                         wp += 256 * 4;
  int* esrc = (int*)wp;                             wp += (size_t)ET * 4;
  unsigned short* wb = (unsigned short*)wp;         wp += 512 * 64 * 2 * 2;

  float* out_sm = (float*)d_out;            // softmax output [N,16]
  float* emb    = out_sm + (size_t)N * 16;  // node_embeddings [N,16]

  const int nb = (N + 1023) / 1024;
  const int nCnt = (E + 255) / 256;

  // CSR build: zero deg, prep_w | count (one dispatch), scans, dedicated scatter
  hipMemsetAsync(deg, 0, (size_t)N * sizeof(int), stream);
  prep_count_kernel<<<128 + nCnt, 256, 0, stream>>>(W1, wb, deg, ei, E);
  scan1_kernel<<<nb, 256, 0, stream>>>(deg, blocksum, N);
  scan2_kernel<<<1, 256, 0, stream>>>(blocksum, nb);
  scan3_kernel<<<(N + 256) / 256, 256, 0, stream>>>(deg, blocksum, rowptr, cursor, N, ET);
  scatter_kernel<<<8 * 1024, 256, 0, stream>>>(ei, E, ET, cursor, esrc, N);

  // layer 1
  gemm1_kernel<<<(N + 127) / 128, 256, 0, stream>>>(x, wb, atts1, attd1, h1b, a1s, a1d, N);
  agg1_kernel<<<(N + 7) / 8, 256, 0, stream>>>(rowptr, esrc, a1s, a1d, h1b, bias1, h2b, N);

  // layer 2
  l2_proj_kernel<<<(N * 16 + 255) / 256, 256, 0, stream>>>(h2b, W2, atts2, attd2, gb, a2s, a2d, N);
  agg2_kernel<<<(N + 7) / 8, 256, 0, stream>>>(rowptr, esrc, a2s, a2d, gb, bias2, out_sm, emb, N);
}

// Round 16
// 328.415 us; speedup vs baseline: 1.1490x; 1.0390x over previous
//
#include <hip/hip_runtime.h>
#include <hip/hip_bf16.h>

#define NEG_SLOPE 0.2f
#define EPSF 1e-16f

typedef __attribute__((ext_vector_type(8))) short bf16x8;
typedef __attribute__((ext_vector_type(4))) float f32x4;

__device__ inline unsigned short f2bf(float x) {
  unsigned int u = __float_as_uint(x);
  return (unsigned short)((u + 0x7fffu + ((u >> 16) & 1u)) >> 16);
}
__device__ inline float bf2f(unsigned short h) {
  return __uint_as_float(((unsigned int)h) << 16);
}

__device__ __forceinline__ void gload16(const void* src, void* dst) {
  __builtin_amdgcn_global_load_lds(
      (const __attribute__((address_space(1))) unsigned int*)src,
      (__attribute__((address_space(3))) unsigned int*)dst, 16, 0, 0);
}

// -------------------- merged: prep_w (blocks 0..127) | count real edges --------------------
// deg pre-zeroed by hipMemsetAsync; self-loops folded into scan3 (+idx), NOT counted here.
__global__ __launch_bounds__(256) void prep_count_kernel(const float* __restrict__ W,
                                                         unsigned short* __restrict__ wb,
                                                         int* __restrict__ deg,
                                                         const int* __restrict__ ei, int E) {
  const int b = blockIdx.x, tid = threadIdx.x;
  if (b < 128) {
    int idx = b * 256 + tid;  // (k:512, c:64)
    int k = idx >> 6, c = idx & 63;
    float w = W[idx];
    unsigned short h = f2bf(w);
    unsigned short l = f2bf(w - bf2f(h));
    int ch = k >> 5, kin = k & 31;
    int Ap = ((c << 6) + (kin << 1)) ^ ((c & 7) << 4);
    wb[ch * 4096 + (Ap >> 1)] = h;
    wb[ch * 4096 + 2048 + (Ap >> 1)] = l;
  } else {
    int e = (b - 128) * 256 + tid;
    if (e < E) atomicAdd(&deg[ei[E + e]], 1);
  }
}

// exclusive scan, stage 1
__global__ __launch_bounds__(256) void scan1_kernel(int* __restrict__ data, int* __restrict__ blocksum, int N) {
  __shared__ int wave_tot[4];
  int t = threadIdx.x;
  int base = blockIdx.x * 1024;
  int v[4];
  int sum = 0;
#pragma unroll
  for (int i = 0; i < 4; ++i) {
    int idx = base + t * 4 + i;
    v[i] = sum;
    int d = (idx < N) ? data[idx] : 0;
    sum += d;
  }
  int lane = t & 63, wv = t >> 6;
  int x = sum;
#pragma unroll
  for (int ofs = 1; ofs < 64; ofs <<= 1) {
    int y = __shfl_up(x, ofs);
    if (lane >= ofs) x += y;
  }
  if (lane == 63) wave_tot[wv] = x;
  __syncthreads();
  int wofs = 0;
  for (int w = 0; w < wv; ++w) wofs += wave_tot[w];
  int excl_thread = wofs + x - sum;
#pragma unroll
  for (int i = 0; i < 4; ++i) {
    int idx = base + t * 4 + i;
    if (idx < N) data[idx] = excl_thread + v[i];
  }
  if (t == 255) blocksum[blockIdx.x] = wofs + x;
}

__global__ __launch_bounds__(256) void scan2_kernel(int* __restrict__ blocksum, int nb) {
  __shared__ int sm[256];
  int t = threadIdx.x;
  int x = (t < nb) ? blocksum[t] : 0;
  sm[t] = x;
  __syncthreads();
  for (int ofs = 1; ofs < 256; ofs <<= 1) {
    int y = (t >= ofs) ? sm[t - ofs] : 0;
    __syncthreads();
    sm[t] += y;
    __syncthreads();
  }
  if (t < nb) blocksum[t] = sm[t] - x;  // exclusive
}

// rowptr[i] = excl_scan(deg)[i] + i  (+i = one self-loop slot per node)
__global__ __launch_bounds__(256) void scan3_kernel(const int* __restrict__ excl, const int* __restrict__ blocksum,
                                                    int* __restrict__ rowptr, int* __restrict__ cursor,
                                                    int N, int ET) {
  int idx = blockIdx.x * 256 + threadIdx.x;
  if (idx < N) {
    int r = excl[idx] + blocksum[idx >> 10] + idx;
    rowptr[idx] = r;
    cursor[idx] = r;
  }
  if (idx == N) rowptr[N] = ET;
}

// XCD-class-filtered scatter (keeps cursor/esrc writes XCD-local); 8192 dedicated blocks
__global__ __launch_bounds__(256) void scatter_kernel(const int* __restrict__ ei, int E, int ET,
                                                      int* __restrict__ cursor, int* __restrict__ esrc, int N) {
  const int cls = blockIdx.x & 7;
  const int nlo = (int)(((long long)N * cls) >> 3);
  const int nhi = (int)(((long long)N * (cls + 1)) >> 3);
  const int chunk = blockIdx.x >> 3;
  const int nchunks = gridDim.x >> 3;
  const long long stride = (long long)nchunks * 256;
  for (long long e = (long long)chunk * 256 + threadIdx.x; e < ET; e += stride) {
    int s, d;
    if (e < E) { d = ei[E + e]; s = ei[e]; }
    else       { d = (int)(e - E); s = d; }
    if (d >= nlo && d < nhi) {
      int pos = atomicAdd(&cursor[d], 1);
      esrc[pos] = s;
    }
  }
}

// -------------------- GEMM1 + fused att1: 3-stage async MFMA pipeline --------------------
__global__ __launch_bounds__(256) void gemm1_kernel(const float* __restrict__ x,
                                                    const unsigned short* __restrict__ wb,
                                                    const float* __restrict__ atts,
                                                    const float* __restrict__ attd,
                                                    unsigned short* __restrict__ h1b,
                                                    float* __restrict__ a1s,
                                                    float* __restrict__ a1d, int N) {
  __shared__ __align__(16) float As[3][4096];          // 48 KB
  __shared__ __align__(16) unsigned short Bs[3][4096]; // 24 KB
  const int tid = threadIdx.x, wv = tid >> 6, lane = tid & 63;
  const int row0 = blockIdx.x * 128;

  const float* asrc[4];
  int aldo[4];
#pragma unroll
  for (int i = 0; i < 4; ++i) {
    int u = i * 256 + wv * 64 + lane;
    int row = u >> 3, w = u & 7;
    int rg = row0 + row;
    if (rg >= N) rg = N - 1;
    asrc[i] = x + (size_t)rg * 512 + ((w ^ (row & 7)) << 2);
    aldo[i] = (i * 256 + wv * 64) * 4;
  }
  const unsigned short* bsrc[2];
  int bldo[2];
#pragma unroll
  for (int i = 0; i < 2; ++i) {
    int u = i * 256 + wv * 64 + lane;
    bsrc[i] = wb + (size_t)u * 8;
    bldo[i] = (i * 256 + wv * 64) * 8;
  }

  const int kofs = (lane >> 4) * 8;
  const int cbase = lane & 15;
  int ardo[2][2];
#pragma unroll
  for (int rt = 0; rt < 2; ++rt) {
    int r = wv * 32 + rt * 16 + cbase;
#pragma unroll
    for (int h = 0; h < 2; ++h)
      ardo[rt][h] = r * 32 + ((((kofs >> 2) + h) ^ (r & 7)) << 2);
  }
  int brdo[4];
#pragma unroll
  for (int ct = 0; ct < 4; ++ct) {
    int c = ct * 16 + cbase;
    brdo[ct] = (((c << 6) + (kofs << 1)) ^ ((c & 7) << 4)) >> 1;
  }

  f32x4 acc[2][4] = {};

  auto stage = [&](int b, int ch) {
#pragma unroll
    for (int i = 0; i < 4; ++i) gload16(asrc[i] + ch * 32, &As[b][aldo[i]]);
#pragma unroll
    for (int i = 0; i < 2; ++i) gload16(bsrc[i] + ch * 4096, &Bs[b][bldo[i]]);
  };

  stage(0, 0);
  stage(1, 1);
  for (int i = 0; i < 16; ++i) {
    const int b = i % 3;
    if (i < 14) {
      stage((i + 2) % 3, i + 2);
      asm volatile("s_waitcnt vmcnt(12)" ::: "memory");
    } else if (i == 14) {
      asm volatile("s_waitcnt vmcnt(6)" ::: "memory");
    } else {
      asm volatile("s_waitcnt vmcnt(0)" ::: "memory");
    }
    __builtin_amdgcn_s_barrier();
    __builtin_amdgcn_sched_barrier(0);

#pragma unroll
    for (int rt = 0; rt < 2; ++rt) {
      float4 a0 = *(const float4*)(&As[b][ardo[rt][0]]);
      float4 a1 = *(const float4*)(&As[b][ardo[rt][1]]);
      float av[8] = {a0.x, a0.y, a0.z, a0.w, a1.x, a1.y, a1.z, a1.w};
      bf16x8 ah, al;
#pragma unroll
      for (int j = 0; j < 8; ++j) {
        unsigned int u = __float_as_uint(av[j]);
        ah[j] = (short)(unsigned short)(u >> 16);
        float lo = av[j] - __uint_as_float(u & 0xffff0000u);
        al[j] = (short)(unsigned short)(__float_as_uint(lo) >> 16);
      }
#pragma unroll
      for (int ct = 0; ct < 4; ++ct) {
        bf16x8 bh = *(const bf16x8*)(&Bs[b][brdo[ct]]);
        bf16x8 bl = *(const bf16x8*)(&Bs[b][brdo[ct] + 2048]);
        acc[rt][ct] = __builtin_amdgcn_mfma_f32_16x16x32_bf16(ah, bh, acc[rt][ct], 0, 0, 0);
        acc[rt][ct] = __builtin_amdgcn_mfma_f32_16x16x32_bf16(al, bh, acc[rt][ct], 0, 0, 0);
        acc[rt][ct] = __builtin_amdgcn_mfma_f32_16x16x32_bf16(ah, bl, acc[rt][ct], 0, 0, 0);
      }
    }
    asm volatile("s_waitcnt lgkmcnt(0)" ::: "memory");
    __builtin_amdgcn_s_barrier();
  }

  float wS[4], wD[4];
#pragma unroll
  for (int ct = 0; ct < 4; ++ct) {
    wS[ct] = atts[ct * 16 + cbase];
    wD[ct] = attd[ct * 16 + cbase];
  }
#pragma unroll
  for (int rt = 0; rt < 2; ++rt) {
#pragma unroll
    for (int ct = 0; ct < 4; ++ct) {
#pragma unroll
      for (int j = 0; j < 4; ++j) {
        int r = row0 + wv * 32 + rt * 16 + (lane >> 4) * 4 + j;
        float a = acc[rt][ct][j];
        if (r < N) h1b[(size_t)r * 64 + ct * 16 + cbase] = f2bf(a);
        float ps = a * wS[ct], pd = a * wD[ct];
        ps += __shfl_xor(ps, 1); pd += __shfl_xor(pd, 1);
        ps += __shfl_xor(ps, 2); pd += __shfl_xor(pd, 2);
        ps += __shfl_xor(ps, 4); pd += __shfl_xor(pd, 4);
        if ((lane & 7) == 0 && r < N) {
          int h = ct * 2 + ((lane >> 3) & 1);
          a1s[r * 8 + h] = ps;
          a1d[r * 8 + h] = pd;
        }
      }
    }
  }
}

// -------------------- agg1: FOUR nodes per wave (16-lane quarters), lane = 4 channels ----------
// quarter q owns node wid*4+q; lane covers channels 4l..4l+3 (one 8B uint2 gather per edge;
// 16 lanes x 8B = 128B coalesced). 2-edge unrolled loop retires 8 edges/wave-iter.
__global__ __launch_bounds__(256) void agg1_kernel(const int* __restrict__ rowptr, const int* __restrict__ esrc,
                                                   const float* __restrict__ a1s, const float* __restrict__ a1d,
                                                   const unsigned short* __restrict__ h1b,
                                                   const float* __restrict__ bias1,
                                                   unsigned short* __restrict__ h2b, int N) {
  const int wid = (blockIdx.x * 256 + threadIdx.x) >> 6;
  const int lane = threadIdx.x & 63;
  const int q = lane >> 4, l = lane & 15;
  const int nA = wid * 4;
  if (nA >= N) return;
  const int n = nA + q;
  const bool nvalid = n < N;
  const int nc = nvalid ? n : nA;
  const int h = l >> 1;          // head of channels 4l..4l+3 (all within one head)
  const int c4 = l * 4;

  const float ad = a1d[(unsigned)nc * 8 + h];
  const int beg = rowptr[nc];
  const int deg = nvalid ? (rowptr[nc + 1] - beg) : 0;
  int dm = max(deg, __shfl_xor(deg, 16));
  dm = max(dm, __shfl_xor(dm, 32));
  const int dcl = max(deg, 1) - 1;

  float acc0 = 0.f, acc1 = 0.f, acc2 = 0.f, acc3 = 0.f, wsum = 0.f;
  for (int it = 0; it < dm; it += 2) {
    int k0 = beg + min(it, dcl);
    int k1 = beg + min(it + 1, dcl);
    float m0 = (it < deg) ? 1.f : 0.f;
    float m1 = (it + 1 < deg) ? 1.f : 0.f;
    int s0 = esrc[k0], s1 = esrc[k1];
    uint2 g0 = *(const uint2*)(h1b + ((unsigned)s0 * 64 + c4));
    uint2 g1 = *(const uint2*)(h1b + ((unsigned)s1 * 64 + c4));
    float al0 = a1s[(unsigned)s0 * 8 + h] + ad;
    float al1 = a1s[(unsigned)s1 * 8 + h] + ad;
    al0 = fmaxf(al0, NEG_SLOPE * al0);
    al1 = fmaxf(al1, NEG_SLOPE * al1);
    float w0 = __expf(al0) * m0;
    float w1 = __expf(al1) * m1;
    acc0 = fmaf(w0, bf2f((unsigned short)(g0.x & 0xffff)), acc0);
    acc1 = fmaf(w0, bf2f((unsigned short)(g0.x >> 16)), acc1);
    acc2 = fmaf(w0, bf2f((unsigned short)(g0.y & 0xffff)), acc2);
    acc3 = fmaf(w0, bf2f((unsigned short)(g0.y >> 16)), acc3);
    acc0 = fmaf(w1, bf2f((unsigned short)(g1.x & 0xffff)), acc0);
    acc1 = fmaf(w1, bf2f((unsigned short)(g1.x >> 16)), acc1);
    acc2 = fmaf(w1, bf2f((unsigned short)(g1.y & 0xffff)), acc2);
    acc3 = fmaf(w1, bf2f((unsigned short)(g1.y >> 16)), acc3);
    wsum += w0 + w1;
  }
  float inv = 1.f / (wsum + EPSF);
  float4 b4 = *(const float4*)(bias1 + c4);
  float v0 = acc0 * inv + b4.x;
  float v1 = acc1 * inv + b4.y;
  float v2 = acc2 * inv + b4.z;
  float v3 = acc3 * inv + b4.w;
  v0 = (v0 > 0.f) ? v0 : expm1f(v0);
  v1 = (v1 > 0.f) ? v1 : expm1f(v1);
  v2 = (v2 > 0.f) ? v2 : expm1f(v2);
  v3 = (v3 > 0.f) ? v3 : expm1f(v3);
  if (nvalid) {
    uint2 pack;
    pack.x = (unsigned int)f2bf(v0) | ((unsigned int)f2bf(v1) << 16);
    pack.y = (unsigned int)f2bf(v2) | ((unsigned int)f2bf(v3) << 16);
    *(uint2*)(h2b + ((unsigned)n * 64 + c4)) = pack;
  }
}

// -------------------- layer2 projection g = h2 @ W2 + attention scalars --------------------
__global__ __launch_bounds__(256) void l2_proj_kernel(const unsigned short* __restrict__ h2b,
                                                      const float* __restrict__ W2,
                                                      const float* __restrict__ atts, const float* __restrict__ attd,
                                                      unsigned short* __restrict__ gb, float* __restrict__ a2s,
                                                      float* __restrict__ a2d, int N) {
  __shared__ float w[1024];
  int tid = threadIdx.x;
  for (int i = tid; i < 1024; i += 256) w[i] = W2[i];
  __syncthreads();
  int gid = blockIdx.x * 256 + tid;
  int n = gid >> 4, c = gid & 15;
  if (n >= N) return;
  const unsigned short* hr = h2b + (size_t)n * 64;
  float acc = 0.f;
#pragma unroll
  for (int k8 = 0; k8 < 8; ++k8) {
    bf16x8 hv = *(const bf16x8*)(hr + k8 * 8);
#pragma unroll
    for (int j = 0; j < 8; ++j)
      acc = fmaf(bf2f((unsigned short)hv[j]), w[(k8 * 8 + j) * 16 + c], acc);
  }
  gb[(size_t)n * 16 + c] = f2bf(acc);
  float ps = acc * atts[c], pd = acc * attd[c];
#pragma unroll
  for (int m = 1; m < 16; m <<= 1) { ps += __shfl_xor(ps, m); pd += __shfl_xor(pd, m); }
  if (c == 0) { a2s[n] = ps; a2d[n] = pd; }
}

// -------------------- agg2: TWO nodes per wave + bias + softmax (fused final) ----------
__global__ __launch_bounds__(256) void agg2_kernel(const int* __restrict__ rowptr, const int* __restrict__ esrc,
                                                   const float* __restrict__ a2s, const float* __restrict__ a2d,
                                                   const unsigned short* __restrict__ gb,
                                                   const float* __restrict__ bias2,
                                                   float* __restrict__ out_sm, float* __restrict__ emb, int N) {
  const int wid = (blockIdx.x * 256 + threadIdx.x) >> 6;
  const int lane = threadIdx.x & 63;
  const int half = lane >> 5, l = lane & 31;
  const int nA = wid * 2;
  if (nA >= N) return;
  const int n = nA + half;
  const bool nvalid = n < N;
  const int nc = nvalid ? n : nA;
  const int c = l & 15, sub = l >> 4;

  const float ad = a2d[nc];
  const int beg = rowptr[nc];
  const int deg = nvalid ? (rowptr[nc + 1] - beg) : 0;
  const int degO = __shfl_xor(deg, 32);
  const int dmax = max(deg, degO);
  const int dcl = max(deg, 1) - 1;

  float acc = 0.f, wsum = 0.f;
  for (int it = 0; it < dmax; it += 2) {
    int k = beg + min(it + sub, dcl);
    float m = (it + sub < deg) ? 1.f : 0.f;
    int s = esrc[k];
    float al = a2s[s] + ad;
    al = fmaxf(al, NEG_SLOPE * al);
    float w = __expf(al) * m;
    acc = fmaf(w, bf2f(gb[(unsigned)s * 16 + c]), acc);
    wsum += w;
  }
  acc += __shfl_xor(acc, 16);
  wsum += __shfl_xor(wsum, 16);
  float v = acc / (wsum + EPSF) + bias2[c];
  float mx = v;
#pragma unroll
  for (int k2 = 1; k2 < 16; k2 <<= 1) mx = fmaxf(mx, __shfl_xor(mx, k2));
  float e = __expf(v - mx);
  float ssum = e;
#pragma unroll
  for (int k2 = 1; k2 < 16; k2 <<= 1) ssum += __shfl_xor(ssum, k2);
  if (sub == 0 && nvalid) {
    emb[(size_t)n * 16 + c] = v;
    out_sm[(size_t)n * 16 + c] = e / ssum;
  }
}

extern "C" void kernel_launch(void* const* d_in, const int* in_sizes, int n_in,
                              void* d_out, int out_size, void* d_ws, size_t ws_size,
                              hipStream_t stream) {
  const float* x     = (const float*)d_in[0];
  const int*   ei    = (const int*)d_in[1];
  const float* W1    = (const float*)d_in[2];
  const float* atts1 = (const float*)d_in[3];
  const float* attd1 = (const float*)d_in[4];
  const float* bias1 = (const float*)d_in[5];
  const float* W2    = (const float*)d_in[6];
  const float* atts2 = (const float*)d_in[7];
  const float* attd2 = (const float*)d_in[8];
  const float* bias2 = (const float*)d_in[9];

  const int N = in_sizes[0] / 512;
  const int E = in_sizes[1] / 2;
  const int ET = E + N;

  char* wp = (char*)d_ws;
  unsigned short* h1b = (unsigned short*)wp;        wp += (size_t)N * 64 * 2;
  unsigned short* h2b = (unsigned short*)wp;        wp += (size_t)N * 64 * 2;
  float* a1s = (float*)wp;                          wp += (size_t)N * 8 * 4;
  float* a1d = (float*)wp;                          wp += (size_t)N * 8 * 4;
  unsigned short* gb = (unsigned short*)wp;         wp += (size_t)N * 16 * 2;
  float* a2s = (float*)wp;                          wp += (size_t)N * 4;
  float* a2d = (float*)wp;                          wp += (size_t)N * 4;
  int* deg = (int*)wp;                              wp += (size_t)N * 4;
  int* rowptr = (int*)wp;                           wp += (size_t)(N + 1) * 4;
  int* cursor = (int*)wp;                           wp += (size_t)N * 4;
  int* blocksum = (int*)wp;                         wp += 256 * 4;
  int* esrc = (int*)wp;                             wp += (size_t)ET * 4;
  unsigned short* wb = (unsigned short*)wp;         wp += 512 * 64 * 2 * 2;

  float* out_sm = (float*)d_out;            // softmax output [N,16]
  float* emb    = out_sm + (size_t)N * 16;  // node_embeddings [N,16]

  const int nb = (N + 1023) / 1024;
  const int nCnt = (E + 255) / 256;

  // CSR build: zero deg, prep_w | count (one dispatch), scans, dedicated scatter
  hipMemsetAsync(deg, 0, (size_t)N * sizeof(int), stream);
  prep_count_kernel<<<128 + nCnt, 256, 0, stream>>>(W1, wb, deg, ei, E);
  scan1_kernel<<<nb, 256, 0, stream>>>(deg, blocksum, N);
  scan2_kernel<<<1, 256, 0, stream>>>(blocksum, nb);
  scan3_kernel<<<(N + 256) / 256, 256, 0, stream>>>(deg, blocksum, rowptr, cursor, N, ET);
  scatter_kernel<<<8 * 1024, 256, 0, stream>>>(ei, E, ET, cursor, esrc, N);

  // layer 1
  gemm1_kernel<<<(N + 127) / 128, 256, 0, stream>>>(x, wb, atts1, attd1, h1b, a1s, a1d, N);
  agg1_kernel<<<(N + 15) / 16, 256, 0, stream>>>(rowptr, esrc, a1s, a1d, h1b, bias1, h2b, N);

  // layer 2
  l2_proj_kernel<<<(N * 16 + 255) / 256, 256, 0, stream>>>(h2b, W2, atts2, attd2, gb, a2s, a2d, N);
  agg2_kernel<<<(N + 7) / 8, 256, 0, stream>>>(rowptr, esrc, a2s, a2d, gb, bias2, out_sm, emb, N);
}

// Round 17
// 313.590 us; speedup vs baseline: 1.2033x; 1.0473x over previous
//
#include <hip/hip_runtime.h>
#include <hip/hip_bf16.h>

#define NEG_SLOPE 0.2f
#define EPSF 1e-16f

typedef __attribute__((ext_vector_type(8))) short bf16x8;
typedef __attribute__((ext_vector_type(4))) float f32x4;

__device__ inline unsigned short f2bf(float x) {
  unsigned int u = __float_as_uint(x);
  return (unsigned short)((u + 0x7fffu + ((u >> 16) & 1u)) >> 16);
}
__device__ inline float bf2f(unsigned short h) {
  return __uint_as_float(((unsigned int)h) << 16);
}

__device__ __forceinline__ void gload16(const void* src, void* dst) {
  __builtin_amdgcn_global_load_lds(
      (const __attribute__((address_space(1))) unsigned int*)src,
      (__attribute__((address_space(3))) unsigned int*)dst, 16, 0, 0);
}

// -------------------- merged: prep_w (blocks 0..127) | count real edges --------------------
__global__ __launch_bounds__(256) void prep_count_kernel(const float* __restrict__ W,
                                                         unsigned short* __restrict__ wb,
                                                         int* __restrict__ deg,
                                                         const int* __restrict__ ei, int E) {
  const int b = blockIdx.x, tid = threadIdx.x;
  if (b < 128) {
    int idx = b * 256 + tid;  // (k:512, c:64)
    int k = idx >> 6, c = idx & 63;
    float w = W[idx];
    unsigned short h = f2bf(w);
    unsigned short l = f2bf(w - bf2f(h));
    int ch = k >> 5, kin = k & 31;
    int Ap = ((c << 6) + (kin << 1)) ^ ((c & 7) << 4);
    wb[ch * 4096 + (Ap >> 1)] = h;
    wb[ch * 4096 + 2048 + (Ap >> 1)] = l;
  } else {
    int e = (b - 128) * 256 + tid;
    if (e < E) atomicAdd(&deg[ei[E + e]], 1);
  }
}

// exclusive scan, stage 1
__global__ __launch_bounds__(256) void scan1_kernel(int* __restrict__ data, int* __restrict__ blocksum, int N) {
  __shared__ int wave_tot[4];
  int t = threadIdx.x;
  int base = blockIdx.x * 1024;
  int v[4];
  int sum = 0;
#pragma unroll
  for (int i = 0; i < 4; ++i) {
    int idx = base + t * 4 + i;
    v[i] = sum;
    int d = (idx < N) ? data[idx] : 0;
    sum += d;
  }
  int lane = t & 63, wv = t >> 6;
  int x = sum;
#pragma unroll
  for (int ofs = 1; ofs < 64; ofs <<= 1) {
    int y = __shfl_up(x, ofs);
    if (lane >= ofs) x += y;
  }
  if (lane == 63) wave_tot[wv] = x;
  __syncthreads();
  int wofs = 0;
  for (int w = 0; w < wv; ++w) wofs += wave_tot[w];
  int excl_thread = wofs + x - sum;
#pragma unroll
  for (int i = 0; i < 4; ++i) {
    int idx = base + t * 4 + i;
    if (idx < N) data[idx] = excl_thread + v[i];
  }
  if (t == 255) blocksum[blockIdx.x] = wofs + x;
}

__global__ __launch_bounds__(256) void scan2_kernel(int* __restrict__ blocksum, int nb) {
  __shared__ int sm[256];
  int t = threadIdx.x;
  int x = (t < nb) ? blocksum[t] : 0;
  sm[t] = x;
  __syncthreads();
  for (int ofs = 1; ofs < 256; ofs <<= 1) {
    int y = (t >= ofs) ? sm[t - ofs] : 0;
    __syncthreads();
    sm[t] += y;
    __syncthreads();
  }
  if (t < nb) blocksum[t] = sm[t] - x;  // exclusive
}

// rowptr[i] = excl_scan(deg)[i] + i  (+i = one self-loop slot per node)
__global__ __launch_bounds__(256) void scan3_kernel(const int* __restrict__ excl, const int* __restrict__ blocksum,
                                                    int* __restrict__ rowptr, int* __restrict__ cursor,
                                                    int N, int ET) {
  int idx = blockIdx.x * 256 + threadIdx.x;
  if (idx < N) {
    int r = excl[idx] + blocksum[idx >> 10] + idx;
    rowptr[idx] = r;
    cursor[idx] = r;
  }
  if (idx == N) rowptr[N] = ET;
}

// XCD-class-filtered scatter; src loaded only for in-range edges (saves 7/8 of src reads)
__global__ __launch_bounds__(256) void scatter_kernel(const int* __restrict__ ei, int E, int ET,
                                                      int* __restrict__ cursor, int* __restrict__ esrc, int N) {
  const int cls = blockIdx.x & 7;
  const int nlo = (int)(((long long)N * cls) >> 3);
  const int nhi = (int)(((long long)N * (cls + 1)) >> 3);
  const int chunk = blockIdx.x >> 3;
  const int nchunks = gridDim.x >> 3;
  const long long stride = (long long)nchunks * 256;
  for (long long e = (long long)chunk * 256 + threadIdx.x; e < ET; e += stride) {
    int d = (e < E) ? ei[E + e] : (int)(e - E);
    if (d >= nlo && d < nhi) {
      int s = (e < E) ? ei[e] : d;
      int pos = atomicAdd(&cursor[d], 1);
      esrc[pos] = s;
    }
  }
}

// -------------------- GEMM1 + fused att1: 3-stage async MFMA pipeline --------------------
__global__ __launch_bounds__(256) void gemm1_kernel(const float* __restrict__ x,
                                                    const unsigned short* __restrict__ wb,
                                                    const float* __restrict__ atts,
                                                    const float* __restrict__ attd,
                                                    unsigned short* __restrict__ h1b,
                                                    float* __restrict__ a1s,
                                                    float* __restrict__ a1d, int N) {
  __shared__ __align__(16) float As[3][4096];          // 48 KB
  __shared__ __align__(16) unsigned short Bs[3][4096]; // 24 KB
  const int tid = threadIdx.x, wv = tid >> 6, lane = tid & 63;
  const int row0 = blockIdx.x * 128;

  const float* asrc[4];
  int aldo[4];
#pragma unroll
  for (int i = 0; i < 4; ++i) {
    int u = i * 256 + wv * 64 + lane;
    int row = u >> 3, w = u & 7;
    int rg = row0 + row;
    if (rg >= N) rg = N - 1;
    asrc[i] = x + (size_t)rg * 512 + ((w ^ (row & 7)) << 2);
    aldo[i] = (i * 256 + wv * 64) * 4;
  }
  const unsigned short* bsrc[2];
  int bldo[2];
#pragma unroll
  for (int i = 0; i < 2; ++i) {
    int u = i * 256 + wv * 64 + lane;
    bsrc[i] = wb + (size_t)u * 8;
    bldo[i] = (i * 256 + wv * 64) * 8;
  }

  const int kofs = (lane >> 4) * 8;
  const int cbase = lane & 15;
  int ardo[2][2];
#pragma unroll
  for (int rt = 0; rt < 2; ++rt) {
    int r = wv * 32 + rt * 16 + cbase;
#pragma unroll
    for (int h = 0; h < 2; ++h)
      ardo[rt][h] = r * 32 + ((((kofs >> 2) + h) ^ (r & 7)) << 2);
  }
  int brdo[4];
#pragma unroll
  for (int ct = 0; ct < 4; ++ct) {
    int c = ct * 16 + cbase;
    brdo[ct] = (((c << 6) + (kofs << 1)) ^ ((c & 7) << 4)) >> 1;
  }

  f32x4 acc[2][4] = {};

  auto stage = [&](int b, int ch) {
#pragma unroll
    for (int i = 0; i < 4; ++i) gload16(asrc[i] + ch * 32, &As[b][aldo[i]]);
#pragma unroll
    for (int i = 0; i < 2; ++i) gload16(bsrc[i] + ch * 4096, &Bs[b][bldo[i]]);
  };

  stage(0, 0);
  stage(1, 1);
  for (int i = 0; i < 16; ++i) {
    const int b = i % 3;
    if (i < 14) {
      stage((i + 2) % 3, i + 2);
      asm volatile("s_waitcnt vmcnt(12)" ::: "memory");
    } else if (i == 14) {
      asm volatile("s_waitcnt vmcnt(6)" ::: "memory");
    } else {
      asm volatile("s_waitcnt vmcnt(0)" ::: "memory");
    }
    __builtin_amdgcn_s_barrier();
    __builtin_amdgcn_sched_barrier(0);

#pragma unroll
    for (int rt = 0; rt < 2; ++rt) {
      float4 a0 = *(const float4*)(&As[b][ardo[rt][0]]);
      float4 a1 = *(const float4*)(&As[b][ardo[rt][1]]);
      float av[8] = {a0.x, a0.y, a0.z, a0.w, a1.x, a1.y, a1.z, a1.w};
      bf16x8 ah, al;
#pragma unroll
      for (int j = 0; j < 8; ++j) {
        unsigned int u = __float_as_uint(av[j]);
        ah[j] = (short)(unsigned short)(u >> 16);
        float lo = av[j] - __uint_as_float(u & 0xffff0000u);
        al[j] = (short)(unsigned short)(__float_as_uint(lo) >> 16);
      }
#pragma unroll
      for (int ct = 0; ct < 4; ++ct) {
        bf16x8 bh = *(const bf16x8*)(&Bs[b][brdo[ct]]);
        bf16x8 bl = *(const bf16x8*)(&Bs[b][brdo[ct] + 2048]);
        acc[rt][ct] = __builtin_amdgcn_mfma_f32_16x16x32_bf16(ah, bh, acc[rt][ct], 0, 0, 0);
        acc[rt][ct] = __builtin_amdgcn_mfma_f32_16x16x32_bf16(al, bh, acc[rt][ct], 0, 0, 0);
        acc[rt][ct] = __builtin_amdgcn_mfma_f32_16x16x32_bf16(ah, bl, acc[rt][ct], 0, 0, 0);
      }
    }
    asm volatile("s_waitcnt lgkmcnt(0)" ::: "memory");
    __builtin_amdgcn_s_barrier();
  }

  float wS[4], wD[4];
#pragma unroll
  for (int ct = 0; ct < 4; ++ct) {
    wS[ct] = atts[ct * 16 + cbase];
    wD[ct] = attd[ct * 16 + cbase];
  }
#pragma unroll
  for (int rt = 0; rt < 2; ++rt) {
#pragma unroll
    for (int ct = 0; ct < 4; ++ct) {
#pragma unroll
      for (int j = 0; j < 4; ++j) {
        int r = row0 + wv * 32 + rt * 16 + (lane >> 4) * 4 + j;
        float a = acc[rt][ct][j];
        if (r < N) h1b[(size_t)r * 64 + ct * 16 + cbase] = f2bf(a);
        float ps = a * wS[ct], pd = a * wD[ct];
        ps += __shfl_xor(ps, 1); pd += __shfl_xor(pd, 1);
        ps += __shfl_xor(ps, 2); pd += __shfl_xor(pd, 2);
        ps += __shfl_xor(ps, 4); pd += __shfl_xor(pd, 4);
        if ((lane & 7) == 0 && r < N) {
          int h = ct * 2 + ((lane >> 3) & 1);
          a1s[r * 8 + h] = ps;
          a1d[r * 8 + h] = pd;
        }
      }
    }
  }
}

// -------------------- agg1: FOUR nodes per wave (16-lane quarters), lane = 4 channels ----------
__global__ __launch_bounds__(256) void agg1_kernel(const int* __restrict__ rowptr, const int* __restrict__ esrc,
                                                   const float* __restrict__ a1s, const float* __restrict__ a1d,
                                                   const unsigned short* __restrict__ h1b,
                                                   const float* __restrict__ bias1,
                                                   unsigned short* __restrict__ h2b, int N) {
  const int wid = (blockIdx.x * 256 + threadIdx.x) >> 6;
  const int lane = threadIdx.x & 63;
  const int q = lane >> 4, l = lane & 15;
  const int nA = wid * 4;
  if (nA >= N) return;
  const int n = nA + q;
  const bool nvalid = n < N;
  const int nc = nvalid ? n : nA;
  const int h = l >> 1;          // head of channels 4l..4l+3
  const int c4 = l * 4;

  const float ad = a1d[(unsigned)nc * 8 + h];
  const int beg = rowptr[nc];
  const int deg = nvalid ? (rowptr[nc + 1] - beg) : 0;
  int dm = max(deg, __shfl_xor(deg, 16));
  dm = max(dm, __shfl_xor(dm, 32));
  const int dcl = max(deg, 1) - 1;

  float acc0 = 0.f, acc1 = 0.f, acc2 = 0.f, acc3 = 0.f, wsum = 0.f;
  for (int it = 0; it < dm; it += 2) {
    int k0 = beg + min(it, dcl);
    int k1 = beg + min(it + 1, dcl);
    float m0 = (it < deg) ? 1.f : 0.f;
    float m1 = (it + 1 < deg) ? 1.f : 0.f;
    int s0 = esrc[k0], s1 = esrc[k1];
    uint2 g0 = *(const uint2*)(h1b + ((unsigned)s0 * 64 + c4));
    uint2 g1 = *(const uint2*)(h1b + ((unsigned)s1 * 64 + c4));
    float al0 = a1s[(unsigned)s0 * 8 + h] + ad;
    float al1 = a1s[(unsigned)s1 * 8 + h] + ad;
    al0 = fmaxf(al0, NEG_SLOPE * al0);
    al1 = fmaxf(al1, NEG_SLOPE * al1);
    float w0 = __expf(al0) * m0;
    float w1 = __expf(al1) * m1;
    acc0 = fmaf(w0, bf2f((unsigned short)(g0.x & 0xffff)), acc0);
    acc1 = fmaf(w0, bf2f((unsigned short)(g0.x >> 16)), acc1);
    acc2 = fmaf(w0, bf2f((unsigned short)(g0.y & 0xffff)), acc2);
    acc3 = fmaf(w0, bf2f((unsigned short)(g0.y >> 16)), acc3);
    acc0 = fmaf(w1, bf2f((unsigned short)(g1.x & 0xffff)), acc0);
    acc1 = fmaf(w1, bf2f((unsigned short)(g1.x >> 16)), acc1);
    acc2 = fmaf(w1, bf2f((unsigned short)(g1.y & 0xffff)), acc2);
    acc3 = fmaf(w1, bf2f((unsigned short)(g1.y >> 16)), acc3);
    wsum += w0 + w1;
  }
  float inv = 1.f / (wsum + EPSF);
  float4 b4 = *(const float4*)(bias1 + c4);
  float v0 = acc0 * inv + b4.x;
  float v1 = acc1 * inv + b4.y;
  float v2 = acc2 * inv + b4.z;
  float v3 = acc3 * inv + b4.w;
  v0 = (v0 > 0.f) ? v0 : expm1f(v0);
  v1 = (v1 > 0.f) ? v1 : expm1f(v1);
  v2 = (v2 > 0.f) ? v2 : expm1f(v2);
  v3 = (v3 > 0.f) ? v3 : expm1f(v3);
  if (nvalid) {
    uint2 pack;
    pack.x = (unsigned int)f2bf(v0) | ((unsigned int)f2bf(v1) << 16);
    pack.y = (unsigned int)f2bf(v2) | ((unsigned int)f2bf(v3) << 16);
    *(uint2*)(h2b + ((unsigned)n * 64 + c4)) = pack;
  }
}

// -------------------- layer2 projection g = h2 @ W2 + attention scalars --------------------
__global__ __launch_bounds__(256) void l2_proj_kernel(const unsigned short* __restrict__ h2b,
                                                      const float* __restrict__ W2,
                                                      const float* __restrict__ atts, const float* __restrict__ attd,
                                                      unsigned short* __restrict__ gb, float* __restrict__ a2s,
                                                      float* __restrict__ a2d, int N) {
  __shared__ float w[1024];
  int tid = threadIdx.x;
  for (int i = tid; i < 1024; i += 256) w[i] = W2[i];
  __syncthreads();
  int gid = blockIdx.x * 256 + tid;
  int n = gid >> 4, c = gid & 15;
  if (n >= N) return;
  const unsigned short* hr = h2b + (size_t)n * 64;
  float acc = 0.f;
#pragma unroll
  for (int k8 = 0; k8 < 8; ++k8) {
    bf16x8 hv = *(const bf16x8*)(hr + k8 * 8);
#pragma unroll
    for (int j = 0; j < 8; ++j)
      acc = fmaf(bf2f((unsigned short)hv[j]), w[(k8 * 8 + j) * 16 + c], acc);
  }
  gb[(size_t)n * 16 + c] = f2bf(acc);
  float ps = acc * atts[c], pd = acc * attd[c];
#pragma unroll
  for (int m = 1; m < 16; m <<= 1) { ps += __shfl_xor(ps, m); pd += __shfl_xor(pd, m); }
  if (c == 0) { a2s[n] = ps; a2d[n] = pd; }
}

// -------------------- agg2: FOUR nodes per wave (16-lane quarters), lane = channel ----------
// quarter q owns node wid*4+q; 2-edge unrolled masked loop -> 8 edges/wave-iter.
// softmax reductions quarter-local (masks 1,2,4,8).
__global__ __launch_bounds__(256) void agg2_kernel(const int* __restrict__ rowptr, const int* __restrict__ esrc,
                                                   const float* __restrict__ a2s, const float* __restrict__ a2d,
                                                   const unsigned short* __restrict__ gb,
                                                   const float* __restrict__ bias2,
                                                   float* __restrict__ out_sm, float* __restrict__ emb, int N) {
  const int wid = (blockIdx.x * 256 + threadIdx.x) >> 6;
  const int lane = threadIdx.x & 63;
  const int q = lane >> 4, c = lane & 15;
  const int nA = wid * 4;
  if (nA >= N) return;
  const int n = nA + q;
  const bool nvalid = n < N;
  const int nc = nvalid ? n : nA;

  const float ad = a2d[nc];
  const int beg = rowptr[nc];
  const int deg = nvalid ? (rowptr[nc + 1] - beg) : 0;
  int dm = max(deg, __shfl_xor(deg, 16));
  dm = max(dm, __shfl_xor(dm, 32));
  const int dcl = max(deg, 1) - 1;

  float acc = 0.f, wsum = 0.f;
  for (int it = 0; it < dm; it += 2) {
    int k0 = beg + min(it, dcl);
    int k1 = beg + min(it + 1, dcl);
    float m0 = (it < deg) ? 1.f : 0.f;
    float m1 = (it + 1 < deg) ? 1.f : 0.f;
    int s0 = esrc[k0], s1 = esrc[k1];
    float al0 = a2s[s0] + ad;
    float al1 = a2s[s1] + ad;
    al0 = fmaxf(al0, NEG_SLOPE * al0);
    al1 = fmaxf(al1, NEG_SLOPE * al1);
    float w0 = __expf(al0) * m0;
    float w1 = __expf(al1) * m1;
    acc = fmaf(w0, bf2f(gb[(unsigned)s0 * 16 + c]), acc);
    acc = fmaf(w1, bf2f(gb[(unsigned)s1 * 16 + c]), acc);
    wsum += w0 + w1;
  }
  float v = acc / (wsum + EPSF) + bias2[c];
  float mx = v;
#pragma unroll
  for (int k2 = 1; k2 < 16; k2 <<= 1) mx = fmaxf(mx, __shfl_xor(mx, k2));
  float e = __expf(v - mx);
  float ssum = e;
#pragma unroll
  for (int k2 = 1; k2 < 16; k2 <<= 1) ssum += __shfl_xor(ssum, k2);
  if (nvalid) {
    emb[(size_t)n * 16 + c] = v;
    out_sm[(size_t)n * 16 + c] = e / ssum;
  }
}

extern "C" void kernel_launch(void* const* d_in, const int* in_sizes, int n_in,
                              void* d_out, int out_size, void* d_ws, size_t ws_size,
                              hipStream_t stream) {
  const float* x     = (const float*)d_in[0];
  const int*   ei    = (const int*)d_in[1];
  const float* W1    = (const float*)d_in[2];
  const float* atts1 = (const float*)d_in[3];
  const float* attd1 = (const float*)d_in[4];
  const float* bias1 = (const float*)d_in[5];
  const float* W2    = (const float*)d_in[6];
  const float* atts2 = (const float*)d_in[7];
  const float* attd2 = (const float*)d_in[8];
  const float* bias2 = (const float*)d_in[9];

  const int N = in_sizes[0] / 512;
  const int E = in_sizes[1] / 2;
  const int ET = E + N;

  char* wp = (char*)d_ws;
  unsigned short* h1b = (unsigned short*)wp;        wp += (size_t)N * 64 * 2;
  unsigned short* h2b = (unsigned short*)wp;        wp += (size_t)N * 64 * 2;
  float* a1s = (float*)wp;                          wp += (size_t)N * 8 * 4;
  float* a1d = (float*)wp;                          wp += (size_t)N * 8 * 4;
  unsigned short* gb = (unsigned short*)wp;         wp += (size_t)N * 16 * 2;
  float* a2s = (float*)wp;                          wp += (size_t)N * 4;
  float* a2d = (float*)wp;                          wp += (size_t)N * 4;
  int* deg = (int*)wp;                              wp += (size_t)N * 4;
  int* rowptr = (int*)wp;                           wp += (size_t)(N + 1) * 4;
  int* cursor = (int*)wp;                           wp += (size_t)N * 4;
  int* blocksum = (int*)wp;                         wp += 256 * 4;
  int* esrc = (int*)wp;                             wp += (size_t)ET * 4;
  unsigned short* wb = (unsigned short*)wp;         wp += 512 * 64 * 2 * 2;

  float* out_sm = (float*)d_out;            // softmax output [N,16]
  float* emb    = out_sm + (size_t)N * 16;  // node_embeddings [N,16]

  const int nb = (N + 1023) / 1024;
  const int nCnt = (E + 255) / 256;

  // CSR build
  hipMemsetAsync(deg, 0, (size_t)N * sizeof(int), stream);
  prep_count_kernel<<<128 + nCnt, 256, 0, stream>>>(W1, wb, deg, ei, E);
  scan1_kernel<<<nb, 256, 0, stream>>>(deg, blocksum, N);
  scan2_kernel<<<1, 256, 0, stream>>>(blocksum, nb);
  scan3_kernel<<<(N + 256) / 256, 256, 0, stream>>>(deg, blocksum, rowptr, cursor, N, ET);
  scatter_kernel<<<8 * 1024, 256, 0, stream>>>(ei, E, ET, cursor, esrc, N);

  // layer 1
  gemm1_kernel<<<(N + 127) / 128, 256, 0, stream>>>(x, wb, atts1, attd1, h1b, a1s, a1d, N);
  agg1_kernel<<<(N + 15) / 16, 256, 0, stream>>>(rowptr, esrc, a1s, a1d, h1b, bias1, h2b, N);

  // layer 2
  l2_proj_kernel<<<(N * 16 + 255) / 256, 256, 0, stream>>>(h2b, W2, atts2, attd2, gb, a2s, a2d, N);
  agg2_kernel<<<(N + 15) / 16, 256, 0, stream>>>(rowptr, esrc, a2s, a2d, gb, bias2, out_sm, emb, N);
}

// Round 18
// 304.014 us; speedup vs baseline: 1.2412x; 1.0315x over previous
//
#include <hip/hip_runtime.h>
#include <hip/hip_bf16.h>

#define NEG_SLOPE 0.2f
#define EPSF 1e-16f

typedef __attribute__((ext_vector_type(8))) short bf16x8;
typedef __attribute__((ext_vector_type(4))) float f32x4;

__device__ inline unsigned short f2bf(float x) {
  unsigned int u = __float_as_uint(x);
  return (unsigned short)((u + 0x7fffu + ((u >> 16) & 1u)) >> 16);
}
__device__ inline float bf2f(unsigned short h) {
  return __uint_as_float(((unsigned int)h) << 16);
}

__device__ __forceinline__ void gload16(const void* src, void* dst) {
  __builtin_amdgcn_global_load_lds(
      (const __attribute__((address_space(1))) unsigned int*)src,
      (__attribute__((address_space(3))) unsigned int*)dst, 16, 0, 0);
}

// -------------------- merged: prep_w (blocks 0..127) | count real edges --------------------
__global__ __launch_bounds__(256) void prep_count_kernel(const float* __restrict__ W,
                                                         unsigned short* __restrict__ wb,
                                                         int* __restrict__ deg,
                                                         const int* __restrict__ ei, int E) {
  const int b = blockIdx.x, tid = threadIdx.x;
  if (b < 128) {
    int idx = b * 256 + tid;  // (k:512, c:64)
    int k = idx >> 6, c = idx & 63;
    float w = W[idx];
    unsigned short h = f2bf(w);
    unsigned short l = f2bf(w - bf2f(h));
    int ch = k >> 5, kin = k & 31;
    int Ap = ((c << 6) + (kin << 1)) ^ ((c & 7) << 4);
    wb[ch * 4096 + (Ap >> 1)] = h;
    wb[ch * 4096 + 2048 + (Ap >> 1)] = l;
  } else {
    int e = (b - 128) * 256 + tid;
    if (e < E) atomicAdd(&deg[ei[E + e]], 1);
  }
}

// exclusive scan, stage 1
__global__ __launch_bounds__(256) void scan1_kernel(int* __restrict__ data, int* __restrict__ blocksum, int N) {
  __shared__ int wave_tot[4];
  int t = threadIdx.x;
  int base = blockIdx.x * 1024;
  int v[4];
  int sum = 0;
#pragma unroll
  for (int i = 0; i < 4; ++i) {
    int idx = base + t * 4 + i;
    v[i] = sum;
    int d = (idx < N) ? data[idx] : 0;
    sum += d;
  }
  int lane = t & 63, wv = t >> 6;
  int x = sum;
#pragma unroll
  for (int ofs = 1; ofs < 64; ofs <<= 1) {
    int y = __shfl_up(x, ofs);
    if (lane >= ofs) x += y;
  }
  if (lane == 63) wave_tot[wv] = x;
  __syncthreads();
  int wofs = 0;
  for (int w = 0; w < wv; ++w) wofs += wave_tot[w];
  int excl_thread = wofs + x - sum;
#pragma unroll
  for (int i = 0; i < 4; ++i) {
    int idx = base + t * 4 + i;
    if (idx < N) data[idx] = excl_thread + v[i];
  }
  if (t == 255) blocksum[blockIdx.x] = wofs + x;
}

// scan3 with fused scan2: each block scans the (<=256-entry) blocksum array in LDS,
// then rowptr[i] = excl_scan(deg)[i] + blocksum_excl[i>>10] + i (+i = self-loop slot)
__global__ __launch_bounds__(256) void scan3_kernel(const int* __restrict__ excl,
                                                    const int* __restrict__ blocksum, int nb,
                                                    int* __restrict__ rowptr, int* __restrict__ cursor,
                                                    int N, int ET) {
  __shared__ int bs[256];
  int t = threadIdx.x;
  int x = (t < nb) ? blocksum[t] : 0;
  bs[t] = x;
  __syncthreads();
  for (int ofs = 1; ofs < 256; ofs <<= 1) {
    int y = (t >= ofs) ? bs[t - ofs] : 0;
    __syncthreads();
    bs[t] += y;
    __syncthreads();
  }
  int ex = bs[t] - x;  // exclusive
  __syncthreads();
  bs[t] = ex;
  __syncthreads();
  int idx = blockIdx.x * 256 + t;
  if (idx < N) {
    int r = excl[idx] + bs[idx >> 10] + idx;
    rowptr[idx] = r;
    cursor[idx] = r;
  }
  if (idx == N) rowptr[N] = ET;
}

// XCD-class-filtered scatter; src loaded only for in-range edges
__global__ __launch_bounds__(256) void scatter_kernel(const int* __restrict__ ei, int E, int ET,
                                                      int* __restrict__ cursor, int* __restrict__ esrc, int N) {
  const int cls = blockIdx.x & 7;
  const int nlo = (int)(((long long)N * cls) >> 3);
  const int nhi = (int)(((long long)N * (cls + 1)) >> 3);
  const int chunk = blockIdx.x >> 3;
  const int nchunks = gridDim.x >> 3;
  const long long stride = (long long)nchunks * 256;
  for (long long e = (long long)chunk * 256 + threadIdx.x; e < ET; e += stride) {
    int d = (e < E) ? ei[E + e] : (int)(e - E);
    if (d >= nlo && d < nhi) {
      int s = (e < E) ? ei[e] : d;
      int pos = atomicAdd(&cursor[d], 1);
      esrc[pos] = s;
    }
  }
}

// -------------------- GEMM1 + fused att1: 3-stage async MFMA pipeline --------------------
__global__ __launch_bounds__(256) void gemm1_kernel(const float* __restrict__ x,
                                                    const unsigned short* __restrict__ wb,
                                                    const float* __restrict__ atts,
                                                    const float* __restrict__ attd,
                                                    unsigned short* __restrict__ h1b,
                                                    float* __restrict__ a1s,
                                                    float* __restrict__ a1d, int N) {
  __shared__ __align__(16) float As[3][4096];          // 48 KB
  __shared__ __align__(16) unsigned short Bs[3][4096]; // 24 KB
  const int tid = threadIdx.x, wv = tid >> 6, lane = tid & 63;
  const int row0 = blockIdx.x * 128;

  const float* asrc[4];
  int aldo[4];
#pragma unroll
  for (int i = 0; i < 4; ++i) {
    int u = i * 256 + wv * 64 + lane;
    int row = u >> 3, w = u & 7;
    int rg = row0 + row;
    if (rg >= N) rg = N - 1;
    asrc[i] = x + (size_t)rg * 512 + ((w ^ (row & 7)) << 2);
    aldo[i] = (i * 256 + wv * 64) * 4;
  }
  const unsigned short* bsrc[2];
  int bldo[2];
#pragma unroll
  for (int i = 0; i < 2; ++i) {
    int u = i * 256 + wv * 64 + lane;
    bsrc[i] = wb + (size_t)u * 8;
    bldo[i] = (i * 256 + wv * 64) * 8;
  }

  const int kofs = (lane >> 4) * 8;
  const int cbase = lane & 15;
  int ardo[2][2];
#pragma unroll
  for (int rt = 0; rt < 2; ++rt) {
    int r = wv * 32 + rt * 16 + cbase;
#pragma unroll
    for (int h = 0; h < 2; ++h)
      ardo[rt][h] = r * 32 + ((((kofs >> 2) + h) ^ (r & 7)) << 2);
  }
  int brdo[4];
#pragma unroll
  for (int ct = 0; ct < 4; ++ct) {
    int c = ct * 16 + cbase;
    brdo[ct] = (((c << 6) + (kofs << 1)) ^ ((c & 7) << 4)) >> 1;
  }

  f32x4 acc[2][4] = {};

  auto stage = [&](int b, int ch) {
#pragma unroll
    for (int i = 0; i < 4; ++i) gload16(asrc[i] + ch * 32, &As[b][aldo[i]]);
#pragma unroll
    for (int i = 0; i < 2; ++i) gload16(bsrc[i] + ch * 4096, &Bs[b][bldo[i]]);
  };

  stage(0, 0);
  stage(1, 1);
  for (int i = 0; i < 16; ++i) {
    const int b = i % 3;
    if (i < 14) {
      stage((i + 2) % 3, i + 2);
      asm volatile("s_waitcnt vmcnt(12)" ::: "memory");
    } else if (i == 14) {
      asm volatile("s_waitcnt vmcnt(6)" ::: "memory");
    } else {
      asm volatile("s_waitcnt vmcnt(0)" ::: "memory");
    }
    __builtin_amdgcn_s_barrier();
    __builtin_amdgcn_sched_barrier(0);

#pragma unroll
    for (int rt = 0; rt < 2; ++rt) {
      float4 a0 = *(const float4*)(&As[b][ardo[rt][0]]);
      float4 a1 = *(const float4*)(&As[b][ardo[rt][1]]);
      float av[8] = {a0.x, a0.y, a0.z, a0.w, a1.x, a1.y, a1.z, a1.w};
      bf16x8 ah, al;
#pragma unroll
      for (int j = 0; j < 8; ++j) {
        unsigned int u = __float_as_uint(av[j]);
        ah[j] = (short)(unsigned short)(u >> 16);
        float lo = av[j] - __uint_as_float(u & 0xffff0000u);
        al[j] = (short)(unsigned short)(__float_as_uint(lo) >> 16);
      }
#pragma unroll
      for (int ct = 0; ct < 4; ++ct) {
        bf16x8 bh = *(const bf16x8*)(&Bs[b][brdo[ct]]);
        bf16x8 bl = *(const bf16x8*)(&Bs[b][brdo[ct] + 2048]);
        acc[rt][ct] = __builtin_amdgcn_mfma_f32_16x16x32_bf16(ah, bh, acc[rt][ct], 0, 0, 0);
        acc[rt][ct] = __builtin_amdgcn_mfma_f32_16x16x32_bf16(al, bh, acc[rt][ct], 0, 0, 0);
        acc[rt][ct] = __builtin_amdgcn_mfma_f32_16x16x32_bf16(ah, bl, acc[rt][ct], 0, 0, 0);
      }
    }
    asm volatile("s_waitcnt lgkmcnt(0)" ::: "memory");
    __builtin_amdgcn_s_barrier();
  }

  float wS[4], wD[4];
#pragma unroll
  for (int ct = 0; ct < 4; ++ct) {
    wS[ct] = atts[ct * 16 + cbase];
    wD[ct] = attd[ct * 16 + cbase];
  }
#pragma unroll
  for (int rt = 0; rt < 2; ++rt) {
#pragma unroll
    for (int ct = 0; ct < 4; ++ct) {
#pragma unroll
      for (int j = 0; j < 4; ++j) {
        int r = row0 + wv * 32 + rt * 16 + (lane >> 4) * 4 + j;
        float a = acc[rt][ct][j];
        if (r < N) h1b[(size_t)r * 64 + ct * 16 + cbase] = f2bf(a);
        float ps = a * wS[ct], pd = a * wD[ct];
        ps += __shfl_xor(ps, 1); pd += __shfl_xor(pd, 1);
        ps += __shfl_xor(ps, 2); pd += __shfl_xor(pd, 2);
        ps += __shfl_xor(ps, 4); pd += __shfl_xor(pd, 4);
        if ((lane & 7) == 0 && r < N) {
          int h = ct * 2 + ((lane >> 3) & 1);
          a1s[r * 8 + h] = ps;
          a1d[r * 8 + h] = pd;
        }
      }
    }
  }
}

// -------------------- agg1 + fused l2_proj: block owns 16 nodes --------------------
// Phase A (per round-17 agg1): 16-lane quarter per node, lane = 4 channels; h2 kept
// in f32 LDS (never written to global). Phase B: thread t computes g[node t>>4][ch t&15]
// as a 64-fma LDS dot with LDS-staged W2, plus a2s/a2d via quarter-local reduce.
__global__ __launch_bounds__(256) void agg1_l2_kernel(const int* __restrict__ rowptr,
                                                      const int* __restrict__ esrc,
                                                      const float* __restrict__ a1s,
                                                      const float* __restrict__ a1d,
                                                      const unsigned short* __restrict__ h1b,
                                                      const float* __restrict__ bias1,
                                                      const float* __restrict__ W2,
                                                      const float* __restrict__ atts2,
                                                      const float* __restrict__ attd2,
                                                      unsigned short* __restrict__ gb,
                                                      float* __restrict__ a2s,
                                                      float* __restrict__ a2d, int N) {
  __shared__ float w2s[1024];
  __shared__ float h2s[16][68];  // padded: no bank conflicts in the dot phase
  const int tid = threadIdx.x;
  const int wv = tid >> 6, lane = tid & 63;
  const int q = lane >> 4, l = lane & 15;
  const int nbase = blockIdx.x * 16;
  const int nloc = wv * 4 + q;
  const int n = nbase + nloc;
  const bool nvalid = n < N;
  const int nc = nvalid ? n : (N - 1);

  for (int i = tid; i < 1024; i += 256) w2s[i] = W2[i];  // covered by the barrier below

  const int h = l >> 1;
  const int c4 = l * 4;
  const float ad = a1d[(unsigned)nc * 8 + h];
  const int beg = rowptr[nc];
  const int deg = nvalid ? (rowptr[nc + 1] - beg) : 0;
  int dm = max(deg, __shfl_xor(deg, 16));
  dm = max(dm, __shfl_xor(dm, 32));
  const int dcl = max(deg, 1) - 1;

  float acc0 = 0.f, acc1 = 0.f, acc2 = 0.f, acc3 = 0.f, wsum = 0.f;
  for (int it = 0; it < dm; it += 2) {
    int k0 = beg + min(it, dcl);
    int k1 = beg + min(it + 1, dcl);
    float m0 = (it < deg) ? 1.f : 0.f;
    float m1 = (it + 1 < deg) ? 1.f : 0.f;
    int s0 = esrc[k0], s1 = esrc[k1];
    uint2 g0 = *(const uint2*)(h1b + ((unsigned)s0 * 64 + c4));
    uint2 g1 = *(const uint2*)(h1b + ((unsigned)s1 * 64 + c4));
    float al0 = a1s[(unsigned)s0 * 8 + h] + ad;
    float al1 = a1s[(unsigned)s1 * 8 + h] + ad;
    al0 = fmaxf(al0, NEG_SLOPE * al0);
    al1 = fmaxf(al1, NEG_SLOPE * al1);
    float w0 = __expf(al0) * m0;
    float w1 = __expf(al1) * m1;
    acc0 = fmaf(w0, bf2f((unsigned short)(g0.x & 0xffff)), acc0);
    acc1 = fmaf(w0, bf2f((unsigned short)(g0.x >> 16)), acc1);
    acc2 = fmaf(w0, bf2f((unsigned short)(g0.y & 0xffff)), acc2);
    acc3 = fmaf(w0, bf2f((unsigned short)(g0.y >> 16)), acc3);
    acc0 = fmaf(w1, bf2f((unsigned short)(g1.x & 0xffff)), acc0);
    acc1 = fmaf(w1, bf2f((unsigned short)(g1.x >> 16)), acc1);
    acc2 = fmaf(w1, bf2f((unsigned short)(g1.y & 0xffff)), acc2);
    acc3 = fmaf(w1, bf2f((unsigned short)(g1.y >> 16)), acc3);
    wsum += w0 + w1;
  }
  float inv = 1.f / (wsum + EPSF);
  float4 b4 = *(const float4*)(bias1 + c4);
  float v0 = acc0 * inv + b4.x;
  float v1 = acc1 * inv + b4.y;
  float v2 = acc2 * inv + b4.z;
  float v3 = acc3 * inv + b4.w;
  v0 = (v0 > 0.f) ? v0 : expm1f(v0);
  v1 = (v1 > 0.f) ? v1 : expm1f(v1);
  v2 = (v2 > 0.f) ? v2 : expm1f(v2);
  v3 = (v3 > 0.f) ? v3 : expm1f(v3);
  h2s[nloc][c4 + 0] = v0;
  h2s[nloc][c4 + 1] = v1;
  h2s[nloc][c4 + 2] = v2;
  h2s[nloc][c4 + 3] = v3;
  __syncthreads();

  // Phase B: l2 projection from LDS
  {
    const int nl2 = tid >> 4, c = tid & 15;
    const int n2 = nbase + nl2;
    float acc = 0.f;
#pragma unroll
    for (int k = 0; k < 64; ++k) acc = fmaf(h2s[nl2][k], w2s[k * 16 + c], acc);
    float ps = acc * atts2[c], pd = acc * attd2[c];
#pragma unroll
    for (int m = 1; m < 16; m <<= 1) { ps += __shfl_xor(ps, m); pd += __shfl_xor(pd, m); }
    if (n2 < N) {
      gb[(size_t)n2 * 16 + c] = f2bf(acc);
      if (c == 0) { a2s[n2] = ps; a2d[n2] = pd; }
    }
  }
}

// -------------------- agg2: FOUR nodes per wave (16-lane quarters), lane = channel ----------
__global__ __launch_bounds__(256) void agg2_kernel(const int* __restrict__ rowptr, const int* __restrict__ esrc,
                                                   const float* __restrict__ a2s, const float* __restrict__ a2d,
                                                   const unsigned short* __restrict__ gb,
                                                   const float* __restrict__ bias2,
                                                   float* __restrict__ out_sm, float* __restrict__ emb, int N) {
  const int wid = (blockIdx.x * 256 + threadIdx.x) >> 6;
  const int lane = threadIdx.x & 63;
  const int q = lane >> 4, c = lane & 15;
  const int nA = wid * 4;
  if (nA >= N) return;
  const int n = nA + q;
  const bool nvalid = n < N;
  const int nc = nvalid ? n : nA;

  const float ad = a2d[nc];
  const int beg = rowptr[nc];
  const int deg = nvalid ? (rowptr[nc + 1] - beg) : 0;
  int dm = max(deg, __shfl_xor(deg, 16));
  dm = max(dm, __shfl_xor(dm, 32));
  const int dcl = max(deg, 1) - 1;

  float acc = 0.f, wsum = 0.f;
  for (int it = 0; it < dm; it += 2) {
    int k0 = beg + min(it, dcl);
    int k1 = beg + min(it + 1, dcl);
    float m0 = (it < deg) ? 1.f : 0.f;
    float m1 = (it + 1 < deg) ? 1.f : 0.f;
    int s0 = esrc[k0], s1 = esrc[k1];
    float al0 = a2s[s0] + ad;
    float al1 = a2s[s1] + ad;
    al0 = fmaxf(al0, NEG_SLOPE * al0);
    al1 = fmaxf(al1, NEG_SLOPE * al1);
    float w0 = __expf(al0) * m0;
    float w1 = __expf(al1) * m1;
    acc = fmaf(w0, bf2f(gb[(unsigned)s0 * 16 + c]), acc);
    acc = fmaf(w1, bf2f(gb[(unsigned)s1 * 16 + c]), acc);
    wsum += w0 + w1;
  }
  float v = acc / (wsum + EPSF) + bias2[c];
  float mx = v;
#pragma unroll
  for (int k2 = 1; k2 < 16; k2 <<= 1) mx = fmaxf(mx, __shfl_xor(mx, k2));
  float e = __expf(v - mx);
  float ssum = e;
#pragma unroll
  for (int k2 = 1; k2 < 16; k2 <<= 1) ssum += __shfl_xor(ssum, k2);
  if (nvalid) {
    emb[(size_t)n * 16 + c] = v;
    out_sm[(size_t)n * 16 + c] = e / ssum;
  }
}

extern "C" void kernel_launch(void* const* d_in, const int* in_sizes, int n_in,
                              void* d_out, int out_size, void* d_ws, size_t ws_size,
                              hipStream_t stream) {
  const float* x     = (const float*)d_in[0];
  const int*   ei    = (const int*)d_in[1];
  const float* W1    = (const float*)d_in[2];
  const float* atts1 = (const float*)d_in[3];
  const float* attd1 = (const float*)d_in[4];
  const float* bias1 = (const float*)d_in[5];
  const float* W2    = (const float*)d_in[6];
  const float* atts2 = (const float*)d_in[7];
  const float* attd2 = (const float*)d_in[8];
  const float* bias2 = (const float*)d_in[9];

  const int N = in_sizes[0] / 512;
  const int E = in_sizes[1] / 2;
  const int ET = E + N;

  char* wp = (char*)d_ws;
  unsigned short* h1b = (unsigned short*)wp;        wp += (size_t)N * 64 * 2;
  float* a1s = (float*)wp;                          wp += (size_t)N * 8 * 4;
  float* a1d = (float*)wp;                          wp += (size_t)N * 8 * 4;
  unsigned short* gb = (unsigned short*)wp;         wp += (size_t)N * 16 * 2;
  float* a2s = (float*)wp;                          wp += (size_t)N * 4;
  float* a2d = (float*)wp;                          wp += (size_t)N * 4;
  int* deg = (int*)wp;                              wp += (size_t)N * 4;
  int* rowptr = (int*)wp;                           wp += (size_t)(N + 1) * 4;
  int* cursor = (int*)wp;                           wp += (size_t)N * 4;
  int* blocksum = (int*)wp;                         wp += 256 * 4;
  int* esrc = (int*)wp;                             wp += (size_t)ET * 4;
  unsigned short* wb = (unsigned short*)wp;         wp += 512 * 64 * 2 * 2;

  float* out_sm = (float*)d_out;            // softmax output [N,16]
  float* emb    = out_sm + (size_t)N * 16;  // node_embeddings [N,16]

  const int nb = (N + 1023) / 1024;
  const int nCnt = (E + 255) / 256;

  // CSR build (scan2 fused into scan3)
  hipMemsetAsync(deg, 0, (size_t)N * sizeof(int), stream);
  prep_count_kernel<<<128 + nCnt, 256, 0, stream>>>(W1, wb, deg, ei, E);
  scan1_kernel<<<nb, 256, 0, stream>>>(deg, blocksum, N);
  scan3_kernel<<<(N + 256) / 256, 256, 0, stream>>>(deg, blocksum, nb, rowptr, cursor, N, ET);
  scatter_kernel<<<8 * 1024, 256, 0, stream>>>(ei, E, ET, cursor, esrc, N);

  // layer 1 (+ fused layer-2 projection)
  gemm1_kernel<<<(N + 127) / 128, 256, 0, stream>>>(x, wb, atts1, attd1, h1b, a1s, a1d, N);
  agg1_l2_kernel<<<(N + 15) / 16, 256, 0, stream>>>(rowptr, esrc, a1s, a1d, h1b, bias1,
                                                    W2, atts2, attd2, gb, a2s, a2d, N);

  // layer 2 aggregation + softmax
  agg2_kernel<<<(N + 15) / 16, 256, 0, stream>>>(rowptr, esrc, a2s, a2d, gb, bias2, out_sm, emb, N);
}